// Round 6
// baseline (2070.921 us; speedup 1.0000x reference)
//
#include <hip/hip_runtime.h>
#include <hip/hip_cooperative_groups.h>

namespace cg = cooperative_groups;

// PageRank, R6: slab-allocated propagation blocking with wave-coalesced
// full-line flushes. R1-R5 established: every global scatter store/atomic =
// one ~32B fabric txn regardless of dtype/scope/run-length (merging happens
// only in the per-instruction wave coalescer). So all bulk writes here are
// 8-lane dwordx4 bursts of full 64B lines from LDS staging windows; bucket
// space is claimed in 32-entry slabs via global cursors (~750K atomics vs
// 32M). No counting-sort pre-pass: edges are read exactly once.

static constexpr int   NN       = 1000000;
static constexpr int   NE       = 16000000;
static constexpr float ALPHA    = 0.85f;
static constexpr int   MAX_ITER = 100;
static constexpr float THRESH   = 1.0f;                      // float32(N)*1e-6
static constexpr float INV_N    = 1.0f / 1000000.0f;
static constexpr float TELEPORT = 0.15f * (1.0f / 1000000.0f);
static constexpr float SCALE    = 8796093022208.0f;          // 2^43
static constexpr float INVSCALE = 1.0f / 8796093022208.0f;

static constexpr int G     = 512;            // grid (2 blocks/CU)
static constexpr int T     = 256;
static constexpr int BSH   = 12;
static constexpr int BSZ   = 4096;           // nodes per bucket
static constexpr int NBA   = 256;            // allocated buckets
static constexpr int NB    = 245;            // used buckets (1M/4096)
static constexpr int CAP   = 65536;          // entry capacity per bucket
static constexpr int CHUNK = NE / G;         // 31250
static constexpr unsigned NEUTRAL_C = 1000000u;  // w[NN] == 0 -> row pad adds 0
static constexpr unsigned short CPAD = 4096;     // deg-hist trash slot

typedef int      vi4 __attribute__((ext_vector_type(4)));
typedef unsigned vu4 __attribute__((ext_vector_type(4)));

template<typename TT>
__device__ __forceinline__ TT ntload(const TT* p) { return __builtin_nontemporal_load(p); }

// ---------------- atomic fallback (is64 input or bucket overflow) ----------------
__device__ void atomic_fallback(cg::grid_group& grid, int is64,
                                const int* e32, const long long* e64,
                                int* ai, int* deg, float* rdeg,
                                float* vA, float* vB, float* w,
                                float* err, float* out,
                                int tid, int stride, int th)
{
    __shared__ float sr[4];
    for (int i = tid; i < NN; i += stride) { ai[i] = 0; deg[i] = 0; vA[i] = INV_N; }
    grid.sync();
    if (is64) { const long long* cols = e64 + NE;
        for (int e = tid; e < NE; e += stride) atomicAdd(&deg[(int)cols[e]], 1); }
    else      { const int* cols = e32 + NE;
        for (int e = tid; e < NE; e += stride) atomicAdd(&deg[cols[e]], 1); }
    grid.sync();
    for (int i = tid; i < NN; i += stride) rdeg[i] = ALPHA / (float)deg[i];
    grid.sync();
    float* v = vA; float* nv = vB;
    for (int iter = 0; iter < MAX_ITER; ++iter) {
        for (int i = tid; i < NN; i += stride) { w[i] = v[i] * rdeg[i]; ai[i] = 0; }
        grid.sync();
        if (is64) { const long long* rows = e64; const long long* cols = e64 + NE;
            for (int e = tid; e < NE; e += stride)
                atomicAdd(&ai[(int)rows[e]], __float2int_rn(w[(int)cols[e]] * SCALE)); }
        else { const int* rows = e32; const int* cols = e32 + NE;
            for (int e = tid; e < NE; e += stride)
                atomicAdd(&ai[rows[e]], __float2int_rn(w[cols[e]] * SCALE)); }
        grid.sync();
        float pe = 0.0f;
        for (int i = tid; i < NN; i += stride) {
            float x = TELEPORT + (float)ai[i] * INVSCALE;
            pe += fabsf(x - v[i]); nv[i] = x;
        }
        #pragma unroll
        for (int off = 32; off > 0; off >>= 1) pe += __shfl_down(pe, off, 64);
        if ((th & 63) == 0) sr[th >> 6] = pe;
        __syncthreads();
        if (th == 0) unsafeAtomicAdd(&err[iter], sr[0] + sr[1] + sr[2] + sr[3]);
        grid.sync();
        float e = ((volatile float*)err)[iter];
        float* t = v; v = nv; nv = t;
        if (e < THRESH) break;
    }
    for (int i = tid; i < NN; i += stride) out[i] = v[i];
}

// ---------------- main kernel ----------------
__global__ __launch_bounds__(256, 2)
void pagerank_pb(const int* __restrict__ e32, const long long* __restrict__ e64,
                 unsigned* __restrict__ prow, unsigned short* __restrict__ pcol,
                 unsigned* __restrict__ gcurR, unsigned* __restrict__ gcurC,
                 int* __restrict__ ovf, int* __restrict__ flags,
                 float* __restrict__ err, float* __restrict__ rdeg,
                 float* __restrict__ vA, float* __restrict__ vB,
                 float* __restrict__ w, float* __restrict__ out)
{
    cg::grid_group grid = cg::this_grid();
    const int th  = threadIdx.x;
    const int blk = blockIdx.x;
    const int tid = blk * T + th;
    const int stride = G * T;

    // LDS: stR 8192 | stC(u16 view) 4096 | lcR/lcC/fdR/fdC/fpR/fpC 6x256 | flag
    __shared__ int SH[13888];
    __shared__ float sred[4];
    int*            stR   = SH;                       // [256][32] u32 entries
    unsigned short* stC16 = (unsigned short*)(SH + 8192);  // [256][32] u16
    int*            stCi  = SH + 8192;                // int view, [256][16]
    int* lcR = SH + 12288; int* lcC = SH + 12544;
    int* fdR = SH + 12800; int* fdC = SH + 13056;
    int* fpR = SH + 13312; int* fpC = SH + 13568;
    int* flg = SH + 13824;

    // ---------------- init ----------------
    if (blk == 0) { gcurR[th] = (unsigned)th * CAP; gcurC[th] = (unsigned)th * CAP; }
    if (tid == 0) {
        *ovf = 0;
        w[NN] = 0.0f;
        int nz = 0;                    // int64 storage => odd words all zero
        for (int k = 1; k < 512; k += 2) nz |= e32[k];
        flags[0] = (nz == 0) ? 1 : 0;
    }
    for (int i = tid; i < MAX_ITER; i += stride) err[i] = 0.0f;
    grid.sync();
    const int is64 = flags[0];

    // ---------------- P3: single-pass bucket scatter ----------------
    if (!is64) {
        const int* rows = e32;
        const int* cols = e32 + NE;
        for (int b = th; b < NBA; b += T) { lcR[b]=0; lcC[b]=0; fdR[b]=0; fdC[b]=0; }
        __syncthreads();

        const int a0 = blk * CHUNK, a1 = a0 + CHUNK;
        const int q0 = a0 >> 2, qmax = (a1 + 3) >> 2;
        const int steps = (qmax - q0 + T - 1) / T;
        const vi4* r4 = (const vi4*)rows;
        const vi4* c4 = (const vi4*)cols;

        for (int s = 0; s < steps; ++s) {
            const int q = q0 + s * T + th;
            int rb[4], cb[4]; unsigned ri[4], ci[4], re[4];
            unsigned short ce[4];
            unsigned pend = 0;
            if (q < qmax) {
                vi4 R = ntload(r4 + q);
                vi4 C = ntload(c4 + q);
                int rr[4] = {R.x, R.y, R.z, R.w};
                int cc[4] = {C.x, C.y, C.z, C.w};
                #pragma unroll
                for (int j = 0; j < 4; ++j) {
                    int e = 4 * q + j;
                    if (e >= a0 && e < a1) {
                        int r = rr[j], c = cc[j];
                        rb[j] = r >> BSH;
                        ri[j] = (unsigned)atomicAdd(&lcR[rb[j]], 1);
                        re[j] = ((unsigned)(r & (BSZ - 1)) << 20) | (unsigned)c;
                        cb[j] = c >> BSH;
                        ci[j] = (unsigned)atomicAdd(&lcC[cb[j]], 1);
                        ce[j] = (unsigned short)(c & (BSZ - 1));
                        pend |= (1u << j) | (1u << (4 + j));
                    }
                }
            }
            // place -> claim -> store, repeat until all placed
            for (;;) {
                if (th == 0) *flg = 0;
                #pragma unroll
                for (int j = 0; j < 4; ++j) {
                    if (pend & (1u << j)) {
                        if ((int)ri[j] < fdR[rb[j]] + 32) {
                            stR[rb[j] * 32 + (ri[j] & 31)] = (int)re[j];
                            pend &= ~(1u << j);
                        }
                    }
                    if (pend & (1u << (4 + j))) {
                        if ((int)ci[j] < fdC[cb[j]] + 32) {
                            stC16[cb[j] * 32 + (ci[j] & 31)] = ce[j];
                            pend &= ~(1u << (4 + j));
                        }
                    }
                }
                __syncthreads();                       // stage visible, lcur stable
                {   // claims: thread th owns bucket th
                    int b = th;
                    int lc = lcR[b], fd = fdR[b];
                    if (lc - fd >= 32) {
                        unsigned pos = atomicAdd(&gcurR[b], 32u);
                        if (pos + 32u > (unsigned)(b + 1) * CAP) { *ovf = 1; pos = 0xFFFFFFFFu; }
                        fpR[b] = (int)pos; fdR[b] = fd + 32;
                    } else fpR[b] = -1;
                    lc = lcC[b]; fd = fdC[b];
                    if (lc - fd >= 32) {
                        unsigned pos = atomicAdd(&gcurC[b], 32u);
                        if (pos + 32u > (unsigned)(b + 1) * CAP) { *ovf = 1; pos = 0xFFFFFFFFu; }
                        fpC[b] = (int)pos; fdC[b] = fd + 32;
                    } else fpC[b] = -1;
                }
                if (pend) *flg = 1;
                __syncthreads();                       // fpos/flag visible
                const int done = (*flg == 0);
                // row stores: 8 rounds x 32 buckets, 8 lanes x dwordx4 = 2 full lines
                #pragma unroll
                for (int r8 = 0; r8 < 8; ++r8) {
                    int b = r8 * 32 + (th >> 3), k = th & 7;
                    int pos = fpR[b];
                    if (pos >= 0) {
                        vi4 v = *(const vi4*)&stR[b * 32 + 4 * k];
                        *(vi4*)(prow + (unsigned)pos + 4 * k) = v;
                    }
                }
                // col stores: 4 rounds x 64 buckets, 4 lanes x dwordx4 = 1 full line
                #pragma unroll
                for (int r4i = 0; r4i < 4; ++r4i) {
                    int b = r4i * 64 + (th >> 2), k = th & 3;
                    int pos = fpC[b];
                    if (pos >= 0) {
                        vi4 v = *(const vi4*)&stCi[b * 16 + 4 * k];
                        *(vi4*)(pcol + (unsigned)pos + 8 * k) = v;
                    }
                }
                __syncthreads();
                if (done) break;
            }
        }
        // tails: claim exact (padded to 16B) and store with padded neutrals
        {
            int b = th;
            { int rem = lcR[b] - fdR[b];
              if (rem > 0) {
                  int prem = (rem + 3) & ~3;
                  unsigned pos = atomicAdd(&gcurR[b], (unsigned)prem);
                  if (pos + (unsigned)prem > (unsigned)(b + 1) * CAP) { *ovf = 1; pos = 0xFFFFFFFFu; }
                  fpR[b] = (int)pos;
              } else fpR[b] = -1; }
            { int rem = lcC[b] - fdC[b];
              if (rem > 0) {
                  int prem = (rem + 7) & ~7;
                  unsigned pos = atomicAdd(&gcurC[b], (unsigned)prem);
                  if (pos + (unsigned)prem > (unsigned)(b + 1) * CAP) { *ovf = 1; pos = 0xFFFFFFFFu; }
                  fpC[b] = (int)pos;
              } else fpC[b] = -1; }
            __syncthreads();
            #pragma unroll
            for (int r8 = 0; r8 < 8; ++r8) {
                int b = r8 * 32 + (th >> 3), k = th & 7;
                int pos = fpR[b];
                if (pos >= 0) {
                    int rem = lcR[b] - fdR[b], prem = (rem + 3) & ~3;
                    #pragma unroll
                    for (int t = 0; t < 4; ++t) {
                        int i = 4 * k + t;
                        if (i < prem)
                            prow[(unsigned)pos + i] = (i < rem) ? (unsigned)stR[b * 32 + i]
                                                                : NEUTRAL_C;   // r_low=0, c=NN
                    }
                }
            }
            #pragma unroll
            for (int r4i = 0; r4i < 4; ++r4i) {
                int b = r4i * 64 + (th >> 2), k = th & 3;
                int pos = fpC[b];
                if (pos >= 0) {
                    int rem = lcC[b] - fdC[b], prem = (rem + 7) & ~7;
                    #pragma unroll
                    for (int t = 0; t < 8; ++t) {
                        int i = 8 * k + t;
                        if (i < prem)
                            pcol[(unsigned)pos + i] = (i < rem) ? stC16[b * 32 + i] : CPAD;
                    }
                }
            }
        }
    }
    grid.sync();

    if (is64 || *ovf) {
        int* ai  = (int*)prow;          // safe: fallback ignores partition arrays
        int* deg = ((int*)prow) + NN;
        atomic_fallback(grid, is64, e32, e64, ai, deg, rdeg, vA, vB, w, err, out,
                        tid, stride, th);
        return;
    }

    // ---------------- P4: per-bucket degree histogram -> rdeg, w0 ----------------
    if (blk < NB) {
        for (int i = th; i <= BSZ; i += T) SH[i] = 0;      // incl. trash slot 4096
        __syncthreads();
        const unsigned base = (unsigned)blk * CAP;
        const unsigned cnt  = gcurC[blk] - base;           // multiple of 8
        const vu4* p8 = (const vu4*)(pcol + base);
        const unsigned nq = cnt >> 3;
        for (unsigned q = th; q < nq; q += T) {
            vu4 x = ntload(p8 + q);
            atomicAdd(&SH[x.x & 0xFFFFu], 1); atomicAdd(&SH[x.x >> 16], 1);
            atomicAdd(&SH[x.y & 0xFFFFu], 1); atomicAdd(&SH[x.y >> 16], 1);
            atomicAdd(&SH[x.z & 0xFFFFu], 1); atomicAdd(&SH[x.z >> 16], 1);
            atomicAdd(&SH[x.w & 0xFFFFu], 1); atomicAdd(&SH[x.w >> 16], 1);
        }
        __syncthreads();
        const int nb = blk * BSZ;
        for (int j = th; j < BSZ; j += T) {
            if (nb + j < NN) {
                float rd = ALPHA / (float)SH[j];   // deg==0 -> inf, never gathered
                rdeg[nb + j] = rd;
                w[nb + j]    = INV_N * rd;         // fused iter-0 phase A
            }
        }
    }
    grid.sync();

    // ---------------- power iterations ----------------
    float* v = vA; float* nv = vB;
    for (int iter = 0; iter < MAX_ITER; ++iter) {
        if (iter > 0) {
            for (int i = tid; i < NN; i += stride) w[i] = v[i] * rdeg[i];
            grid.sync();
        }
        float pe = 0.0f;
        if (blk < NB) {
            for (int i = th; i < BSZ; i += T) SH[i] = 0;
            __syncthreads();
            const unsigned base = (unsigned)blk * CAP;
            const unsigned cnt  = gcurR[blk] - base;       // multiple of 4
            const vu4* p4 = (const vu4*)(prow + base);
            const unsigned nq = cnt >> 2;
            #pragma unroll 2
            for (unsigned q = th; q < nq; q += T) {
                vu4 pk = ntload(p4 + q);
                atomicAdd(&SH[pk.x >> 20], __float2int_rn(w[pk.x & 0xFFFFFu] * SCALE));
                atomicAdd(&SH[pk.y >> 20], __float2int_rn(w[pk.y & 0xFFFFFu] * SCALE));
                atomicAdd(&SH[pk.z >> 20], __float2int_rn(w[pk.z & 0xFFFFFu] * SCALE));
                atomicAdd(&SH[pk.w >> 20], __float2int_rn(w[pk.w & 0xFFFFFu] * SCALE));
            }
            __syncthreads();
            const int nb = blk * BSZ;
            for (int j = th; j < BSZ; j += T) {
                int idx = nb + j;
                if (idx < NN) {
                    float x = TELEPORT + (float)SH[j] * INVSCALE;
                    float vi = (iter == 0) ? INV_N : v[idx];
                    pe += fabsf(x - vi);
                    nv[idx] = x;
                }
            }
        }
        #pragma unroll
        for (int off = 32; off > 0; off >>= 1) pe += __shfl_down(pe, off, 64);
        if ((th & 63) == 0) sred[th >> 6] = pe;
        __syncthreads();
        if (th == 0 && blk < NB)
            unsafeAtomicAdd(&err[iter], sred[0] + sred[1] + sred[2] + sred[3]);
        grid.sync();
        const float e = ((volatile float*)err)[iter];
        float* t = v; v = nv; nv = t;
        if (e < THRESH) break;
    }

    const float4* vf = (const float4*)v;
    float4* of = (float4*)out;
    for (int i = tid; i < NN / 4; i += stride) of[i] = vf[i];
}

// ---- emergency fallback kernel (ws too small / occupancy short) ----
__global__ __launch_bounds__(256, 4)
void pagerank_atomic(const int* __restrict__ e32, const long long* __restrict__ e64,
                     int* __restrict__ ai, int* __restrict__ deg,
                     float* __restrict__ rdeg, float* __restrict__ vA,
                     float* __restrict__ vB, float* __restrict__ w,
                     float* __restrict__ err, int* __restrict__ flags,
                     float* __restrict__ out)
{
    cg::grid_group grid = cg::this_grid();
    const int tid = blockIdx.x * blockDim.x + threadIdx.x;
    const int stride = gridDim.x * blockDim.x;
    for (int i = tid; i < MAX_ITER; i += stride) err[i] = 0.0f;
    if (tid == 0) {
        int nz = 0;
        for (int k = 1; k < 512; k += 2) nz |= e32[k];
        flags[0] = (nz == 0) ? 1 : 0;
    }
    grid.sync();
    atomic_fallback(grid, flags[0], e32, e64, ai, deg, rdeg, vA, vB, w, err, out,
                    tid, stride, threadIdx.x);
}

extern "C" void kernel_launch(void* const* d_in, const int* in_sizes, int n_in,
                              void* d_out, int out_size, void* d_ws, size_t ws_size,
                              hipStream_t stream)
{
    (void)n_in; (void)out_size;
    const int*       e32 = (const int*)d_in[1];
    const long long* e64 = (const long long*)d_in[1];
    float* out = (float*)d_out;
    char* ws = (char*)d_ws;

    const size_t OFF_PROW = 0;                       // 256*65536*4 = 67,108,864
    const size_t OFF_PCOL = 67108864;                // 256*65536*2 = 33,554,432
    const size_t OFF_CTRL = 100663296;               // gcurR|gcurC|ovf|flags|err
    const size_t OFF_RDEG = 100667392;               // 4,000,000
    const size_t OFF_W    = 104667392;               // 4,000,016 (w[NN] slot)
    const size_t NEED     = 108667408;

    int occ = 0;
    hipOccupancyMaxActiveBlocksPerMultiprocessor(&occ, (const void*)pagerank_pb, T, 0);

    if (ws_size >= NEED && occ >= 2) {
        unsigned*       prow  = (unsigned*)(ws + OFF_PROW);
        unsigned short* pcol  = (unsigned short*)(ws + OFF_PCOL);
        unsigned*       gcurR = (unsigned*)(ws + OFF_CTRL);
        unsigned*       gcurC = (unsigned*)(ws + OFF_CTRL + 1024);
        int*            ovf   = (int*)(ws + OFF_CTRL + 2048);
        int*            flags = (int*)(ws + OFF_CTRL + 2112);
        float*          err   = (float*)(ws + OFF_CTRL + 2176);
        float*          rdeg  = (float*)(ws + OFF_RDEG);
        float*          vA    = (float*)(ws + OFF_PCOL);             // overlay (pcol dead after P4)
        float*          vB    = (float*)(ws + OFF_PCOL + 4194304);
        float*          w     = (float*)(ws + OFF_W);
        void* args[] = { (void*)&e32, (void*)&e64, (void*)&prow, (void*)&pcol,
                         (void*)&gcurR, (void*)&gcurC, (void*)&ovf, (void*)&flags,
                         (void*)&err, (void*)&rdeg, (void*)&vA, (void*)&vB,
                         (void*)&w, (void*)&out };
        hipLaunchCooperativeKernel((const void*)pagerank_pb,
                                   dim3(G), dim3(T), args, 0, stream);
        return;
    }

    // emergency: device-atomic version, small footprint
    const size_t MB = 1024 * 1024;
    int*   ai    = (int*)(ws);
    int*   deg   = (int*)(ws + 4 * MB);
    float* rdeg  = (float*)(ws + 8 * MB);
    float* vA    = (float*)(ws + 12 * MB);
    float* vB    = (float*)(ws + 16 * MB);
    float* w     = (float*)(ws + 20 * MB);
    float* err   = (float*)(ws + 24 * MB);
    int*   flg   = (int*)(ws + 24 * MB + 4096);
    int occ2 = 0;
    hipOccupancyMaxActiveBlocksPerMultiprocessor(&occ2, (const void*)pagerank_atomic, 256, 0);
    if (occ2 < 1) occ2 = 1;
    int grid = occ2 * 256; if (grid > 2048) grid = 2048;
    void* args[] = { (void*)&e32, (void*)&e64, (void*)&ai, (void*)&deg, (void*)&rdeg,
                     (void*)&vA, (void*)&vB, (void*)&w, (void*)&err, (void*)&flg,
                     (void*)&out };
    hipLaunchCooperativeKernel((const void*)pagerank_atomic,
                               dim3(grid), dim3(256), args, 0, stream);
}

// Round 7
// 1160.063 us; speedup vs baseline: 1.7852x; 1.7852x over previous
//
#include <hip/hip_runtime.h>
#include <hip/hip_cooperative_groups.h>

namespace cg = cooperative_groups;

// PageRank R7: exact-placement propagation blocking, all bulk writes are
// contiguous whole-wave bursts. Session law (R1-R6): scatter-shaped global
// stores/atomics cost ~32B fabric-write per lane-access regardless of dtype/
// scope/grouping; only long contiguous wave bursts write at ideal bytes.
// Design: 64 row-buckets (16K nodes; 64KB LDS accumulator in SpMV) and 64
// col-buckets (64KB LDS degree hist). P1 hist + scans give exact per-
// (block,bucket) offsets; P3 stages in 128-entry LDS rings, flushing
// 64-entry contiguous chunks. Buckets padded to x8 with neutral entries.

static constexpr int   NN       = 1000000;
static constexpr int   NE       = 16000000;
static constexpr float ALPHA    = 0.85f;
static constexpr int   MAX_ITER = 100;
static constexpr float THRESH   = 1.0f;                      // float32(N)*1e-6
static constexpr float INV_N    = 1.0f / 1000000.0f;
static constexpr float TELEPORT = 0.15f * (1.0f / 1000000.0f);
static constexpr float SCALE    = 8796093022208.0f;          // 2^43
static constexpr float INVSCALE = 1.0f / 8796093022208.0f;

static constexpr int G     = 512;
static constexpr int T     = 256;
static constexpr int CHUNK = NE / G;         // 31250
static constexpr int BSH   = 14;
static constexpr int BKN   = 16384;          // nodes per bucket
static constexpr int NBK   = 64;             // buckets (61.04 used)

typedef int      vi4 __attribute__((ext_vector_type(4)));
typedef unsigned vu4 __attribute__((ext_vector_type(4)));

template<typename TT>
__device__ __forceinline__ TT ntload(const TT* p) { return __builtin_nontemporal_load(p); }

// ---- atomic fallback (is64 input / ring overflow / small ws). No __shared__. ----
__device__ void atomic_fallback(cg::grid_group& grid, int is64,
                                const int* e32, const long long* e64,
                                int* ai, int* deg, float* rdeg,
                                float* vA, float* vB, float* w,
                                float* err, float* out,
                                int tid, int stride, int th, int nblk)
{
    for (int i = tid; i < NN; i += stride) { ai[i] = 0; deg[i] = 0; vA[i] = INV_N; }
    grid.sync();
    if (is64) { const long long* cols = e64 + NE;
        for (int e = tid; e < NE; e += stride) atomicAdd(&deg[(int)cols[e]], 1); }
    else      { const int* cols = e32 + NE;
        for (int e = tid; e < NE; e += stride) atomicAdd(&deg[cols[e]], 1); }
    grid.sync();
    for (int i = tid; i < NN; i += stride) rdeg[i] = ALPHA / (float)deg[i];
    grid.sync();
    float* v = vA; float* nv = vB;
    for (int iter = 0; iter < MAX_ITER; ++iter) {
        for (int i = tid; i < NN; i += stride) { w[i] = v[i] * rdeg[i]; ai[i] = 0; }
        grid.sync();
        if (is64) { const long long* rows = e64; const long long* cols = e64 + NE;
            for (int e = tid; e < NE; e += stride)
                atomicAdd(&ai[(int)rows[e]], __float2int_rn(w[(int)cols[e]] * SCALE)); }
        else { const int* rows = e32; const int* cols = e32 + NE;
            for (int e = tid; e < NE; e += stride)
                atomicAdd(&ai[rows[e]], __float2int_rn(w[cols[e]] * SCALE)); }
        grid.sync();
        float pe = 0.0f;
        for (int i = tid; i < NN; i += stride) {
            float x = TELEPORT + (float)ai[i] * INVSCALE;
            pe += fabsf(x - v[i]); nv[i] = x;
        }
        #pragma unroll
        for (int off = 32; off > 0; off >>= 1) pe += __shfl_down(pe, off, 64);
        if ((th & 63) == 0) unsafeAtomicAdd(&err[iter], pe);
        grid.sync();
        float e = ((volatile float*)err)[iter];
        float* t = v; v = nv; nv = t;
        if (e < THRESH) break;
    }
    for (int i = tid; i < NN; i += stride) out[i] = v[i];
}

__global__ __launch_bounds__(256, 2)
void pagerank_r7(const int* __restrict__ e32, const long long* __restrict__ e64,
                 unsigned* __restrict__ wcg,       // row-bucketed c (u32)
                 unsigned short* __restrict__ wrg, // row-bucketed r&16383 (u16)
                 unsigned short* __restrict__ pcg, // col-bucketed c&16383 (u16)
                 unsigned* __restrict__ cntR, unsigned* __restrict__ cntC, // [64*512]
                 unsigned* __restrict__ ctrl,
                 float* __restrict__ rdeg, float* __restrict__ w,
                 float* __restrict__ v, float* __restrict__ out,
                 char* __restrict__ wsbase)
{
    cg::grid_group grid = cg::this_grid();
    const int th  = threadIdx.x;
    const int blk = blockIdx.x;
    const int tid = blk * T + th;
    const int stride = G * T;

    __shared__ int SH[16384];          // 64 KB exactly; no other __shared__

    unsigned* totR  = ctrl;            // [64]
    unsigned* totC  = ctrl + 64;       // [64]
    unsigned* baseR = ctrl + 128;      // [65]
    unsigned* baseC = ctrl + 200;      // [65]
    unsigned* flags = ctrl + 280;
    int*      ovfG  = (int*)(ctrl + 281);
    float*    errF  = (float*)(ctrl + 288);   // [128]

    // ---------------- init ----------------
    for (int i = tid; i < MAX_ITER; i += stride) errF[i] = 0.0f;
    if (tid == 0) {
        *ovfG = 0;
        w[NN] = 0.0f;                  // neutral gather slot for row pads
        int nz = 0;                    // int64 storage => odd words all zero
        for (int k = 1; k < 512; k += 2) nz |= e32[k];
        flags[0] = (nz == 0) ? 1u : 0u;
    }
    grid.sync();
    const int is64 = (int)flags[0];

    const vi4* R4 = (const vi4*)e32;
    const vi4* C4 = (const vi4*)(e32 + NE);
    const int a0 = blk * CHUNK, a1 = a0 + CHUNK;

    if (!is64) {
        // ---------------- P1: per-chunk bucket histograms ----------------
        if (th < 128) SH[th] = 0;
        __syncthreads();
        {
            const int qlo = a0 >> 2, qhi = (a1 + 3) >> 2;
            for (int q = qlo + th; q < qhi; q += T) {
                vi4 R = ntload(R4 + q), C = ntload(C4 + q);
                int rr[4] = {R.x, R.y, R.z, R.w};
                int cc[4] = {C.x, C.y, C.z, C.w};
                #pragma unroll
                for (int j = 0; j < 4; ++j) {
                    int e = 4 * q + j;
                    if (e >= a0 && e < a1) {
                        atomicAdd(&SH[rr[j] >> BSH], 1);
                        atomicAdd(&SH[64 + (cc[j] >> BSH)], 1);
                    }
                }
            }
        }
        __syncthreads();
        if (th < 64) { cntR[th * G + blk] = (unsigned)SH[th];
                       cntC[th * G + blk] = (unsigned)SH[64 + th]; }
        grid.sync();

        // ---------------- P2a: per-bucket exclusive scan over 512 blocks ----------------
        if (blk < 128) {
            unsigned* cnt = (blk < 64) ? cntR : cntC;
            const int b = blk & 63;
            unsigned c0 = cnt[b * G + 2 * th], c1 = cnt[b * G + 2 * th + 1];
            unsigned s = c0 + c1;
            SH[th] = (int)s; __syncthreads();
            for (int off = 1; off < 256; off <<= 1) {
                int x = (th >= off) ? SH[th - off] : 0;
                __syncthreads();
                SH[th] += x;
                __syncthreads();
            }
            unsigned excl = (unsigned)SH[th] - s;
            cnt[b * G + 2 * th]     = excl;
            cnt[b * G + 2 * th + 1] = excl + c0;
            if (th == 255) ((blk < 64) ? totR : totC)[b] = (unsigned)SH[255];
        }
        grid.sync();

        // ---------------- P2b: padded bucket bases ----------------
        if (blk == 0) {
            unsigned pt = 0;
            if (th < 128) {
                unsigned t = (th < 64) ? totR[th] : totC[th - 64];
                pt = (t + 7u) & ~7u;
                SH[th] = (int)pt;
            }
            __syncthreads();
            for (int off = 1; off < 64; off <<= 1) {
                int x = (th < 128 && (th & 63) >= off) ? SH[th - off] : 0;
                __syncthreads();
                if (th < 128) SH[th] += x;
                __syncthreads();
            }
            if (th < 64) {
                baseR[th] = (unsigned)SH[th] - pt;
                if (th == 63) baseR[64] = (unsigned)SH[63];
            } else if (th < 128) {
                baseC[th - 64] = (unsigned)SH[th] - pt;
                if (th == 127) baseC[64] = (unsigned)SH[127];
            }
        }
        grid.sync();

        // ---------------- pads (disjoint from P3 output ranges) ----------------
        if (blk < 128) {
            const int side = blk >> 6, b = blk & 63;
            unsigned tot = side ? totC[b] : totR[b];
            unsigned bs  = side ? baseC[b] : baseR[b];
            unsigned pt  = (tot + 7u) & ~7u;
            if ((unsigned)th < pt - tot) {
                unsigned p = bs + tot + (unsigned)th;
                if (side) pcg[p] = 0;                     // deg corrected in P4
                else      { wcg[p] = (unsigned)NN; wrg[p] = 0; }
            }
        }

        // ---------------- P3-row: staged scatter, contiguous 64-entry flushes ----------------
        {
            int*            wcL = SH;                             // [64][128] u32
            unsigned short* wrL = (unsigned short*)(SH + 8192);   // [64][128] u16
            int* fills = SH + 12288; int* flsh = SH + 12352; int* wpos = SH + 12416;
            __syncthreads();
            if (th < 64) { fills[th] = 0; flsh[th] = 0;
                           wpos[th] = (int)(baseR[th] + cntR[th * G + blk]); }
            __syncthreads();
            for (int b0 = a0; b0 < a1; b0 += 1024) {
                const int b1 = min(a1, b0 + 1024);
                const int qlo = b0 >> 2, qhi = (b1 + 3) >> 2;
                for (int q = qlo + th; q < qhi; q += T) {
                    vi4 R = ntload(R4 + q), C = ntload(C4 + q);
                    int rr[4] = {R.x, R.y, R.z, R.w};
                    int cc[4] = {C.x, C.y, C.z, C.w};
                    #pragma unroll
                    for (int j = 0; j < 4; ++j) {
                        int e = 4 * q + j;
                        if (e >= b0 && e < b1) {
                            int bb = rr[j] >> BSH;
                            int idx = atomicAdd(&fills[bb], 1);
                            int sl = idx & 127;
                            wcL[bb * 128 + sl] = cc[j];
                            wrL[bb * 128 + sl] = (unsigned short)(rr[j] & (BKN - 1));
                        }
                    }
                }
                __syncthreads();
                const int wv = th >> 6, lane = th & 63;
                for (int k = 0; k < 16; ++k) {
                    const int b = wv * 16 + k;
                    int ff = fills[b], fl = flsh[b], wp = wpos[b];
                    if (ff - fl > 128) *ovfG = 1;         // ring wrapped (p ~ 0)
                    while (ff - fl >= 64) {
                        wcg[wp + lane] = (unsigned)wcL[b * 128 + ((fl + lane) & 127)];
                        wrg[wp + lane] = wrL[b * 128 + ((fl + lane) & 127)];
                        fl += 64; wp += 64;
                    }
                    if (lane == 0) { flsh[b] = fl; wpos[b] = wp; }
                }
                __syncthreads();
            }
            {   // drain
                const int wv = th >> 6, lane = th & 63;
                for (int k = 0; k < 16; ++k) {
                    const int b = wv * 16 + k;
                    int ff = fills[b], fl = flsh[b], wp = wpos[b];
                    while (ff > fl) {
                        int n = min(64, ff - fl);
                        if (lane < n) {
                            wcg[wp + lane] = (unsigned)wcL[b * 128 + ((fl + lane) & 127)];
                            wrg[wp + lane] = wrL[b * 128 + ((fl + lane) & 127)];
                        }
                        fl += n; wp += n;
                    }
                }
            }
            __syncthreads();
        }

        // ---------------- P3-col: same machinery, u16 entries ----------------
        {
            unsigned short* pcL = (unsigned short*)SH;            // [64][128] u16
            int* fills = SH + 4096; int* flsh = SH + 4160; int* wpos = SH + 4224;
            if (th < 64) { fills[th] = 0; flsh[th] = 0;
                           wpos[th] = (int)(baseC[th] + cntC[th * G + blk]); }
            __syncthreads();
            for (int b0 = a0; b0 < a1; b0 += 1024) {
                const int b1 = min(a1, b0 + 1024);
                const int qlo = b0 >> 2, qhi = (b1 + 3) >> 2;
                for (int q = qlo + th; q < qhi; q += T) {
                    vi4 C = ntload(C4 + q);
                    int cc[4] = {C.x, C.y, C.z, C.w};
                    #pragma unroll
                    for (int j = 0; j < 4; ++j) {
                        int e = 4 * q + j;
                        if (e >= b0 && e < b1) {
                            int bb = cc[j] >> BSH;
                            int idx = atomicAdd(&fills[bb], 1);
                            pcL[bb * 128 + (idx & 127)] =
                                (unsigned short)(cc[j] & (BKN - 1));
                        }
                    }
                }
                __syncthreads();
                const int wv = th >> 6, lane = th & 63;
                for (int k = 0; k < 16; ++k) {
                    const int b = wv * 16 + k;
                    int ff = fills[b], fl = flsh[b], wp = wpos[b];
                    if (ff - fl > 128) *ovfG = 1;
                    while (ff - fl >= 64) {
                        pcg[wp + lane] = pcL[b * 128 + ((fl + lane) & 127)];
                        fl += 64; wp += 64;
                    }
                    if (lane == 0) { flsh[b] = fl; wpos[b] = wp; }
                }
                __syncthreads();
            }
            {   // drain
                const int wv = th >> 6, lane = th & 63;
                for (int k = 0; k < 16; ++k) {
                    const int b = wv * 16 + k;
                    int ff = fills[b], fl = flsh[b], wp = wpos[b];
                    while (ff > fl) {
                        int n = min(64, ff - fl);
                        if (lane < n)
                            pcg[wp + lane] = pcL[b * 128 + ((fl + lane) & 127)];
                        fl += n; wp += n;
                    }
                }
            }
        }
    }
    grid.sync();

    if (is64 || *ovfG) {
        int*   ai   = (int*)wsbase;
        int*   deg  = (int*)(wsbase + (size_t)4  * 1024 * 1024);
        float* vA   = (float*)(wsbase + (size_t)8  * 1024 * 1024);
        float* vB   = (float*)(wsbase + (size_t)12 * 1024 * 1024);
        float* wF   = (float*)(wsbase + (size_t)16 * 1024 * 1024);
        atomic_fallback(grid, is64, e32, e64, ai, deg, rdeg, vA, vB, wF,
                        errF, out, tid, stride, th, G);
        return;
    }

    // ---------------- P4: degree hist -> rdeg, w0 ----------------
    if (blk < NBK) {
        for (int j = th; j < BKN; j += T) SH[j] = 0;
        __syncthreads();
        const unsigned bs = baseC[blk], tot = totC[blk], pt = (tot + 7u) & ~7u;
        const vu4* p8 = (const vu4*)(pcg + bs);
        const unsigned nq = pt >> 3;
        for (unsigned q = th; q < nq; q += T) {
            vu4 x = ntload(p8 + q);
            atomicAdd(&SH[x.x & 0xFFFFu], 1); atomicAdd(&SH[x.x >> 16], 1);
            atomicAdd(&SH[x.y & 0xFFFFu], 1); atomicAdd(&SH[x.y >> 16], 1);
            atomicAdd(&SH[x.z & 0xFFFFu], 1); atomicAdd(&SH[x.z >> 16], 1);
            atomicAdd(&SH[x.w & 0xFFFFu], 1); atomicAdd(&SH[x.w >> 16], 1);
        }
        __syncthreads();
        if (th == 0) SH[0] -= (int)(pt - tot);      // remove col pads
        __syncthreads();
        const int nb = blk * BKN;
        for (int j = th; j < BKN; j += T) {
            int node = nb + j;
            if (node < NN) {
                float rd = ALPHA / (float)SH[j];    // deg==0 -> inf, never gathered
                rdeg[node] = rd;
                w[node]    = INV_N * rd;            // fused iter-0 phase A
            }
        }
    }
    grid.sync();

    // ---------------- power iterations (v committed in place) ----------------
    for (int iter = 0; iter < MAX_ITER; ++iter) {
        if (iter > 0) {
            for (int i = tid; i < NN; i += stride) w[i] = v[i] * rdeg[i];
            grid.sync();
        }
        float pe = 0.0f;
        if (blk < NBK) {
            for (int j = th; j < BKN; j += T) SH[j] = 0;
            __syncthreads();
            const unsigned bs = baseR[blk], tot = totR[blk], pt = (tot + 7u) & ~7u;
            const vu4* r8 = (const vu4*)(wrg + bs);
            const vi4* c8 = (const vi4*)(wcg + bs);
            const unsigned nq = pt >> 3;
            for (unsigned q = th; q < nq; q += T) {
                vu4 rl = ntload(r8 + q);
                vi4 ca = ntload(c8 + 2 * q), cb = ntload(c8 + 2 * q + 1);
                atomicAdd(&SH[rl.x & 0xFFFFu], __float2int_rn(w[(unsigned)ca.x] * SCALE));
                atomicAdd(&SH[rl.x >> 16],     __float2int_rn(w[(unsigned)ca.y] * SCALE));
                atomicAdd(&SH[rl.y & 0xFFFFu], __float2int_rn(w[(unsigned)ca.z] * SCALE));
                atomicAdd(&SH[rl.y >> 16],     __float2int_rn(w[(unsigned)ca.w] * SCALE));
                atomicAdd(&SH[rl.z & 0xFFFFu], __float2int_rn(w[(unsigned)cb.x] * SCALE));
                atomicAdd(&SH[rl.z >> 16],     __float2int_rn(w[(unsigned)cb.y] * SCALE));
                atomicAdd(&SH[rl.w & 0xFFFFu], __float2int_rn(w[(unsigned)cb.z] * SCALE));
                atomicAdd(&SH[rl.w >> 16],     __float2int_rn(w[(unsigned)cb.w] * SCALE));
            }
            __syncthreads();
            const int nb = blk * BKN;
            for (int j = th; j < BKN; j += T) {
                int node = nb + j;
                if (node < NN) {
                    float x  = TELEPORT + (float)SH[j] * INVSCALE;
                    float vi = (iter == 0) ? INV_N : v[node];
                    pe += fabsf(x - vi);
                    v[node] = x;                    // in-place commit
                }
            }
        }
        #pragma unroll
        for (int off = 32; off > 0; off >>= 1) pe += __shfl_down(pe, off, 64);
        if ((th & 63) == 0 && blk < NBK) unsafeAtomicAdd(&errF[iter], pe);
        grid.sync();
        const float e = ((volatile float*)errF)[iter];
        if (e < THRESH) break;
    }

    const float4* vf = (const float4*)v;
    float4* of = (float4*)out;
    for (int i = tid; i < NN / 4; i += stride) of[i] = vf[i];
}

// ---- emergency fallback kernel (ws too small / occupancy short) ----
__global__ __launch_bounds__(256, 4)
void pagerank_atomic(const int* __restrict__ e32, const long long* __restrict__ e64,
                     int* __restrict__ ai, int* __restrict__ deg,
                     float* __restrict__ rdeg, float* __restrict__ vA,
                     float* __restrict__ vB, float* __restrict__ w,
                     float* __restrict__ err, int* __restrict__ flags,
                     float* __restrict__ out)
{
    cg::grid_group grid = cg::this_grid();
    const int tid = blockIdx.x * blockDim.x + threadIdx.x;
    const int stride = gridDim.x * blockDim.x;
    for (int i = tid; i < MAX_ITER; i += stride) err[i] = 0.0f;
    if (tid == 0) {
        int nz = 0;
        for (int k = 1; k < 512; k += 2) nz |= e32[k];
        flags[0] = (nz == 0) ? 1 : 0;
    }
    grid.sync();
    atomic_fallback(grid, flags[0], e32, e64, ai, deg, rdeg, vA, vB, w, err, out,
                    tid, stride, threadIdx.x, gridDim.x);
}

extern "C" void kernel_launch(void* const* d_in, const int* in_sizes, int n_in,
                              void* d_out, int out_size, void* d_ws, size_t ws_size,
                              hipStream_t stream)
{
    (void)n_in; (void)out_size;
    const int*       e32 = (const int*)d_in[1];
    const long long* e64 = (const long long*)d_in[1];
    float* out = (float*)d_out;
    char* ws = (char*)d_ws;

    // layout (all offsets 16B-aligned); ENT = NE + 64*8 pad slack
    const size_t OFF_WC   = 0;                   // 16,000,512 u32 = 64,002,048
    const size_t OFF_WR   = 64002048;            // 16,000,512 u16 = 32,001,024
    const size_t OFF_PC   = 96003072;            // 32,001,024
    const size_t OFF_CNTR = 128004096;           // 64*512 u32 = 131,072
    const size_t OFF_CNTC = 128135168;           // 131,072
    const size_t OFF_CTRL = 128266240;           // 4,096
    const size_t OFF_RDEG = 128270336;           // 4,000,000
    const size_t OFF_W    = 132270336;           // 4,000,128 (incl. w[NN] slot)
    const size_t OFF_V    = 136270464;           // 4,000,000
    const size_t NEED     = 140270464;

    int occ = 0;
    hipOccupancyMaxActiveBlocksPerMultiprocessor(&occ, (const void*)pagerank_r7, T, 0);

    if (ws_size >= NEED && occ >= 2) {
        unsigned*       wcg  = (unsigned*)(ws + OFF_WC);
        unsigned short* wrg  = (unsigned short*)(ws + OFF_WR);
        unsigned short* pcg  = (unsigned short*)(ws + OFF_PC);
        unsigned*       cntR = (unsigned*)(ws + OFF_CNTR);
        unsigned*       cntC = (unsigned*)(ws + OFF_CNTC);
        unsigned*       ctrl = (unsigned*)(ws + OFF_CTRL);
        float*          rdeg = (float*)(ws + OFF_RDEG);
        float*          w    = (float*)(ws + OFF_W);
        float*          v    = (float*)(ws + OFF_V);
        void* args[] = { (void*)&e32, (void*)&e64, (void*)&wcg, (void*)&wrg,
                         (void*)&pcg, (void*)&cntR, (void*)&cntC, (void*)&ctrl,
                         (void*)&rdeg, (void*)&w, (void*)&v, (void*)&out,
                         (void*)&ws };
        hipLaunchCooperativeKernel((const void*)pagerank_r7,
                                   dim3(G), dim3(T), args, 0, stream);
        return;
    }

    // emergency: device-atomic version, small footprint
    const size_t MB = 1024 * 1024;
    int*   ai    = (int*)(ws);
    int*   deg   = (int*)(ws + 4 * MB);
    float* rdeg  = (float*)(ws + 8 * MB);
    float* vA    = (float*)(ws + 12 * MB);
    float* vB    = (float*)(ws + 16 * MB);
    float* w     = (float*)(ws + 20 * MB);
    float* err   = (float*)(ws + 24 * MB);
    int*   flg   = (int*)(ws + 24 * MB + 4096);
    int occ2 = 0;
    hipOccupancyMaxActiveBlocksPerMultiprocessor(&occ2, (const void*)pagerank_atomic, 256, 0);
    if (occ2 < 1) occ2 = 1;
    int grid = occ2 * 256; if (grid > 2048) grid = 2048;
    void* args[] = { (void*)&e32, (void*)&e64, (void*)&ai, (void*)&deg, (void*)&rdeg,
                     (void*)&vA, (void*)&vB, (void*)&w, (void*)&err, (void*)&flg,
                     (void*)&out };
    hipLaunchCooperativeKernel((const void*)pagerank_atomic,
                               dim3(grid), dim3(256), args, 0, stream);
}

// Round 8
// 1111.020 us; speedup vs baseline: 1.8640x; 1.0441x over previous
//
#include <hip/hip_runtime.h>
#include <hip/hip_cooperative_groups.h>

namespace cg = cooperative_groups;

// PageRank R8: R7's validated partitioner (exact placement, whole-wave
// contiguous flushes -> WRITE_SIZE 170MB ~= ideal) + 8x-parallel consumption.
// R7 ran P4/SpMV on 64 blocks (1/8 of chip): ~300us of stream+gather time
// serialized on 32 CUs. R8: 496 blocks each accumulate a private 64KB LDS
// partial over 1/8 of a bucket's edges, written as a contiguous NT burst;
// 489-block merge sums 8 partials/slice. Degree hist gets the same 8-way
// treatment (u16 partials). d_out doubles as v; w-recompute fused into merge.

static constexpr int   NN       = 1000000;
static constexpr int   NE       = 16000000;
static constexpr float ALPHA    = 0.85f;
static constexpr int   MAX_ITER = 100;
static constexpr float THRESH   = 1.0f;                      // float32(N)*1e-6
static constexpr float INV_N    = 1.0f / 1000000.0f;
static constexpr float TELEPORT = 0.15f * (1.0f / 1000000.0f);
static constexpr float SCALE    = 8796093022208.0f;          // 2^43
static constexpr float INVSCALE = 1.0f / 8796093022208.0f;

static constexpr int G     = 512;
static constexpr int T     = 256;
static constexpr int CHUNK = NE / G;         // 31250
static constexpr int BSH   = 14;
static constexpr int BKN   = 16384;          // nodes per bucket
static constexpr int NBK   = 64;             // allocated buckets (62 used)
static constexpr int NSUBB = 496;            // 62 buckets x 8 subs
static constexpr int NSLC  = 489;            // 2048-node merge slices

// ws layout (bytes). colp+hpart overlay wcg (dead before P3-row writes wcg).
static constexpr size_t OFF_WCG  = 0;                  // 16,000,512 u32
static constexpr size_t OFF_COLP = 0;                  // 16,000,512 u16 (overlay)
static constexpr size_t OFF_HP   = 32001024;           // 496*16384 u16 (overlay)
static constexpr size_t OFF_WRG  = 64002048;           // 16,000,512 u16
static constexpr size_t OFF_PACC = 96003072;           // 496*16384 i32
static constexpr size_t OFF_CNTR = 128508928;          // 64*512 u32
static constexpr size_t OFF_CNTC = 128640000;          // 64*512 u32
static constexpr size_t OFF_CTRL = 128771072;          // 4 KB
static constexpr size_t OFF_RDEG = 128775168;          // 4,000,000
static constexpr size_t OFF_W    = 132775168;          // 4,000,032 (w[NN] slot)
static constexpr size_t NEED     = 136775200;

typedef int      vi4 __attribute__((ext_vector_type(4)));
typedef unsigned vu4 __attribute__((ext_vector_type(4)));

template<typename TT>
__device__ __forceinline__ TT ntload(const TT* p) { return __builtin_nontemporal_load(p); }

// ---- atomic fallback (is64 input / ring overflow / small ws). No __shared__. ----
__device__ void atomic_fallback(cg::grid_group& grid, int is64,
                                const int* e32, const long long* e64,
                                int* ai, int* deg, float* rdeg,
                                float* vA, float* vB, float* w,
                                float* err, float* out,
                                int tid, int stride, int th)
{
    for (int i = tid; i < NN; i += stride) { ai[i] = 0; deg[i] = 0; vA[i] = INV_N; }
    grid.sync();
    if (is64) { const long long* cols = e64 + NE;
        for (int e = tid; e < NE; e += stride) atomicAdd(&deg[(int)cols[e]], 1); }
    else      { const int* cols = e32 + NE;
        for (int e = tid; e < NE; e += stride) atomicAdd(&deg[cols[e]], 1); }
    grid.sync();
    for (int i = tid; i < NN; i += stride) rdeg[i] = ALPHA / (float)deg[i];
    grid.sync();
    float* v = vA; float* nv = vB;
    for (int iter = 0; iter < MAX_ITER; ++iter) {
        for (int i = tid; i < NN; i += stride) { w[i] = v[i] * rdeg[i]; ai[i] = 0; }
        grid.sync();
        if (is64) { const long long* rows = e64; const long long* cols = e64 + NE;
            for (int e = tid; e < NE; e += stride)
                atomicAdd(&ai[(int)rows[e]], __float2int_rn(w[(int)cols[e]] * SCALE)); }
        else { const int* rows = e32; const int* cols = e32 + NE;
            for (int e = tid; e < NE; e += stride)
                atomicAdd(&ai[rows[e]], __float2int_rn(w[cols[e]] * SCALE)); }
        grid.sync();
        float pe = 0.0f;
        for (int i = tid; i < NN; i += stride) {
            float x = TELEPORT + (float)ai[i] * INVSCALE;
            pe += fabsf(x - v[i]); nv[i] = x;
        }
        #pragma unroll
        for (int off = 32; off > 0; off >>= 1) pe += __shfl_down(pe, off, 64);
        if ((th & 63) == 0) unsafeAtomicAdd(&err[iter], pe);
        grid.sync();
        float e = ((volatile float*)err)[iter];
        float* t = v; v = nv; nv = t;
        if (e < THRESH) break;
    }
    for (int i = tid; i < NN; i += stride) out[i] = v[i];
}

__global__ __launch_bounds__(256, 2)
void pagerank_r8(const int* __restrict__ e32, const long long* __restrict__ e64,
                 char* __restrict__ ws, float* __restrict__ out)
{
    cg::grid_group grid = cg::this_grid();
    const int th  = threadIdx.x;
    const int blk = blockIdx.x;
    const int tid = blk * T + th;
    const int stride = G * T;

    unsigned*       wcg  = (unsigned*)(ws + OFF_WCG);
    unsigned short* colp = (unsigned short*)(ws + OFF_COLP);
    unsigned short* hpart= (unsigned short*)(ws + OFF_HP);
    unsigned short* wrg  = (unsigned short*)(ws + OFF_WRG);
    int*            pacc = (int*)(ws + OFF_PACC);
    unsigned*       cntR = (unsigned*)(ws + OFF_CNTR);
    unsigned*       cntC = (unsigned*)(ws + OFF_CNTC);
    unsigned*       ctrl = (unsigned*)(ws + OFF_CTRL);
    float*          rdeg = (float*)(ws + OFF_RDEG);
    float*          w    = (float*)(ws + OFF_W);

    unsigned* totR  = ctrl;
    unsigned* totC  = ctrl + 64;
    unsigned* baseR = ctrl + 128;       // [65]
    unsigned* baseC = ctrl + 200;       // [65]
    unsigned* flags = ctrl + 280;
    int*      ovfG  = (int*)(ctrl + 281);
    float*    errF  = (float*)(ctrl + 288);

    __shared__ int SH[16384];
    __shared__ float sred[4];

    // ---------------- init ----------------
    if (tid < MAX_ITER) errF[tid] = 0.0f;
    if (tid == 0) {
        *ovfG = 0;
        w[NN] = 0.0f;                   // neutral gather slot for row pads
        int nz = 0;                     // int64 storage => odd words all zero
        for (int k = 1; k < 512; k += 2) nz |= e32[k];
        flags[0] = (nz == 0) ? 1u : 0u;
    }
    grid.sync();
    const int is64 = (int)flags[0];

    if (is64) {
        atomic_fallback(grid, 1, e32, e64,
                        (int*)ws, (int*)(ws + (size_t)4*1024*1024), rdeg,
                        (float*)(ws + (size_t)8*1024*1024),
                        (float*)(ws + (size_t)12*1024*1024),
                        (float*)(ws + (size_t)16*1024*1024),
                        errF, out, tid, stride, th);
        return;
    }

    const vi4* R4 = (const vi4*)e32;
    const vi4* C4 = (const vi4*)(e32 + NE);
    const int a0 = blk * CHUNK, a1 = a0 + CHUNK;

    // ---------------- P1: per-chunk bucket histograms (rows & cols) ----------------
    if (th < 128) SH[th] = 0;
    __syncthreads();
    {
        const int qlo = a0 >> 2, qhi = (a1 + 3) >> 2;
        for (int q = qlo + th; q < qhi; q += T) {
            vi4 R = ntload(R4 + q), C = ntload(C4 + q);
            int rr[4] = {R.x, R.y, R.z, R.w};
            int cc[4] = {C.x, C.y, C.z, C.w};
            #pragma unroll
            for (int j = 0; j < 4; ++j) {
                int e = 4 * q + j;
                if (e >= a0 && e < a1) {
                    atomicAdd(&SH[rr[j] >> BSH], 1);
                    atomicAdd(&SH[64 + (cc[j] >> BSH)], 1);
                }
            }
        }
    }
    __syncthreads();
    if (th < 64) { cntR[th * G + blk] = (unsigned)SH[th];
                   cntC[th * G + blk] = (unsigned)SH[64 + th]; }
    grid.sync();

    // ---------------- P2a: per-bucket exclusive scan over 512 blocks ----------------
    if (blk < 128) {
        unsigned* cnt = (blk < 64) ? cntR : cntC;
        const int b = blk & 63;
        unsigned c0 = cnt[b * G + 2 * th], c1 = cnt[b * G + 2 * th + 1];
        unsigned s = c0 + c1;
        SH[th] = (int)s; __syncthreads();
        for (int off = 1; off < 256; off <<= 1) {
            int x = (th >= off) ? SH[th - off] : 0;
            __syncthreads();
            SH[th] += x;
            __syncthreads();
        }
        unsigned excl = (unsigned)SH[th] - s;
        cnt[b * G + 2 * th]     = excl;
        cnt[b * G + 2 * th + 1] = excl + c0;
        if (th == 255) ((blk < 64) ? totR : totC)[b] = (unsigned)SH[255];
    }
    grid.sync();

    // ---------------- P2b: padded bucket bases (x8 aligned) ----------------
    if (blk == 0) {
        unsigned pt = 0;
        if (th < 128) {
            unsigned t = (th < 64) ? totR[th] : totC[th - 64];
            pt = (t + 7u) & ~7u;
            SH[th] = (int)pt;
        }
        __syncthreads();
        for (int off = 1; off < 64; off <<= 1) {
            int x = (th < 128 && (th & 63) >= off) ? SH[th - off] : 0;
            __syncthreads();
            if (th < 128) SH[th] += x;
            __syncthreads();
        }
        if (th < 64) {
            baseR[th] = (unsigned)SH[th] - pt;
            if (th == 63) baseR[64] = (unsigned)SH[63];
        } else if (th < 128) {
            baseC[th - 64] = (unsigned)SH[th] - pt;
            if (th == 127) baseC[64] = (unsigned)SH[127];
        }
    }
    grid.sync();

    // ---------------- P3-col: staged scatter of c&16383 into col buckets ----------------
    {
        if (blk >= 64 && blk < 128) {            // col pads (disjoint from appends)
            const int b = blk - 64;
            unsigned tot = totC[b], bs = baseC[b], pt = (tot + 7u) & ~7u;
            if ((unsigned)th < pt - tot) colp[bs + tot + (unsigned)th] = 0;
        }
        unsigned short* pcL = (unsigned short*)SH;            // [64][128] u16
        int* fills = SH + 4096; int* flsh = SH + 4160; int* wpos = SH + 4224;
        if (th < 64) { fills[th] = 0; flsh[th] = 0;
                       wpos[th] = (int)(baseC[th] + cntC[th * G + blk]); }
        __syncthreads();
        for (int b0 = a0; b0 < a1; b0 += 1024) {
            const int b1 = min(a1, b0 + 1024);
            const int qlo = b0 >> 2, qhi = (b1 + 3) >> 2;
            for (int q = qlo + th; q < qhi; q += T) {
                vi4 C = ntload(C4 + q);
                int cc[4] = {C.x, C.y, C.z, C.w};
                #pragma unroll
                for (int j = 0; j < 4; ++j) {
                    int e = 4 * q + j;
                    if (e >= b0 && e < b1) {
                        int bb = cc[j] >> BSH;
                        int idx = atomicAdd(&fills[bb], 1);
                        pcL[bb * 128 + (idx & 127)] =
                            (unsigned short)(cc[j] & (BKN - 1));
                    }
                }
            }
            __syncthreads();
            const int wv = th >> 6, lane = th & 63;
            for (int k = 0; k < 16; ++k) {
                const int b = wv * 16 + k;
                int ff = fills[b], fl = flsh[b], wp = wpos[b];
                if (ff - fl > 128) *ovfG = 1;
                while (ff - fl >= 64) {
                    colp[wp + lane] = pcL[b * 128 + ((fl + lane) & 127)];
                    fl += 64; wp += 64;
                }
                if (lane == 0) { flsh[b] = fl; wpos[b] = wp; }
            }
            __syncthreads();
        }
        {   // drain
            const int wv = th >> 6, lane = th & 63;
            for (int k = 0; k < 16; ++k) {
                const int b = wv * 16 + k;
                int ff = fills[b], fl = flsh[b], wp = wpos[b];
                while (ff > fl) {
                    int n = min(64, ff - fl);
                    if (lane < n)
                        colp[wp + lane] = pcL[b * 128 + ((fl + lane) & 127)];
                    fl += n; wp += n;
                }
            }
        }
    }
    grid.sync();

    if (*ovfG) {
        atomic_fallback(grid, 0, e32, e64,
                        (int*)ws, (int*)(ws + (size_t)4*1024*1024), rdeg,
                        (float*)(ws + (size_t)8*1024*1024),
                        (float*)(ws + (size_t)12*1024*1024),
                        (float*)(ws + (size_t)16*1024*1024),
                        errF, out, tid, stride, th);
        return;
    }

    // ---------------- P4-A: 8-way degree partial histograms ----------------
    if (blk < NSUBB) {
        const int b = blk >> 3, sub = blk & 7;
        for (int j = th; j < 16384; j += T) SH[j] = 0;
        __syncthreads();
        const unsigned bs = baseC[b], tot = totC[b], pt = (tot + 7u) & ~7u;
        const unsigned nq = pt >> 3;
        const unsigned qlo = (nq * (unsigned)sub) >> 3;
        const unsigned qhi = (nq * (unsigned)(sub + 1)) >> 3;
        const vu4* p8 = (const vu4*)colp + (bs >> 3);
        for (unsigned q = qlo + th; q < qhi; q += T) {
            vu4 x = ntload(p8 + q);
            atomicAdd(&SH[x.x & 0xFFFFu], 1); atomicAdd(&SH[x.x >> 16], 1);
            atomicAdd(&SH[x.y & 0xFFFFu], 1); atomicAdd(&SH[x.y >> 16], 1);
            atomicAdd(&SH[x.z & 0xFFFFu], 1); atomicAdd(&SH[x.z >> 16], 1);
            atomicAdd(&SH[x.w & 0xFFFFu], 1); atomicAdd(&SH[x.w >> 16], 1);
        }
        __syncthreads();
        unsigned* hp = (unsigned*)(hpart + (size_t)blk * 16384);
        for (int j = th; j < 8192; j += T)
            __builtin_nontemporal_store(
                (unsigned)((SH[2*j] & 0xFFFF) | (SH[2*j+1] << 16)), hp + j);
    }
    grid.sync();

    // ---------------- P4-B: merge partials -> rdeg, w0 ----------------
    if (blk < NSLC) {
        const int b = blk >> 3, off = (blk & 7) * 2048;
        const unsigned padC = ((totC[b] + 7u) & ~7u) - totC[b];
        for (int j = th; j < 1024; j += T) {
            unsigned lo = 0, hi = 0;
            #pragma unroll
            for (int p = 0; p < 8; ++p) {
                const unsigned* hp = (const unsigned*)(hpart + (size_t)(b*8+p)*16384 + off);
                unsigned x = ntload(hp + j);
                lo += x & 0xFFFFu; hi += x >> 16;
            }
            if (off == 0 && j == 0) lo -= padC;
            int node = b * BKN + off + 2 * j;
            if (node < NN) {
                float r0 = ALPHA / (float)(int)lo;   // deg==0 -> inf, never gathered
                float r1 = ALPHA / (float)(int)hi;
                float2 rr = {r0, r1};
                *(float2*)&rdeg[node] = rr;
                float2 ww = {INV_N * r0, INV_N * r1};
                *(float2*)&w[node] = ww;
            }
        }
    }
    grid.sync();

    // ---------------- P3-row: staged scatter (c | r_low) into row buckets ----------------
    {
        if (blk < 64) {                          // row pads
            unsigned tot = totR[blk], bs = baseR[blk], pt = (tot + 7u) & ~7u;
            if ((unsigned)th < pt - tot) {
                wcg[bs + tot + (unsigned)th] = (unsigned)NN;   // w[NN]=0 neutral
                wrg[bs + tot + (unsigned)th] = 0;
            }
        }
        int*            wcL = SH;                             // [64][128] u32
        unsigned short* wrL = (unsigned short*)(SH + 8192);   // [64][128] u16
        int* fills = SH + 12288; int* flsh = SH + 12352; int* wpos = SH + 12416;
        __syncthreads();
        if (th < 64) { fills[th] = 0; flsh[th] = 0;
                       wpos[th] = (int)(baseR[th] + cntR[th * G + blk]); }
        __syncthreads();
        for (int b0 = a0; b0 < a1; b0 += 1024) {
            const int b1 = min(a1, b0 + 1024);
            const int qlo = b0 >> 2, qhi = (b1 + 3) >> 2;
            for (int q = qlo + th; q < qhi; q += T) {
                vi4 R = ntload(R4 + q), C = ntload(C4 + q);
                int rr[4] = {R.x, R.y, R.z, R.w};
                int cc[4] = {C.x, C.y, C.z, C.w};
                #pragma unroll
                for (int j = 0; j < 4; ++j) {
                    int e = 4 * q + j;
                    if (e >= b0 && e < b1) {
                        int bb = rr[j] >> BSH;
                        int idx = atomicAdd(&fills[bb], 1);
                        int sl = idx & 127;
                        wcL[bb * 128 + sl] = cc[j];
                        wrL[bb * 128 + sl] = (unsigned short)(rr[j] & (BKN - 1));
                    }
                }
            }
            __syncthreads();
            const int wv = th >> 6, lane = th & 63;
            for (int k = 0; k < 16; ++k) {
                const int b = wv * 16 + k;
                int ff = fills[b], fl = flsh[b], wp = wpos[b];
                if (ff - fl > 128) *ovfG = 1;
                while (ff - fl >= 64) {
                    wcg[wp + lane] = (unsigned)wcL[b * 128 + ((fl + lane) & 127)];
                    wrg[wp + lane] = wrL[b * 128 + ((fl + lane) & 127)];
                    fl += 64; wp += 64;
                }
                if (lane == 0) { flsh[b] = fl; wpos[b] = wp; }
            }
            __syncthreads();
        }
        {   // drain
            const int wv = th >> 6, lane = th & 63;
            for (int k = 0; k < 16; ++k) {
                const int b = wv * 16 + k;
                int ff = fills[b], fl = flsh[b], wp = wpos[b];
                while (ff > fl) {
                    int n = min(64, ff - fl);
                    if (lane < n) {
                        wcg[wp + lane] = (unsigned)wcL[b * 128 + ((fl + lane) & 127)];
                        wrg[wp + lane] = wrL[b * 128 + ((fl + lane) & 127)];
                    }
                    fl += n; wp += n;
                }
            }
        }
    }
    grid.sync();

    if (*ovfG) {
        atomic_fallback(grid, 0, e32, e64,
                        (int*)ws, (int*)(ws + (size_t)4*1024*1024), rdeg,
                        (float*)(ws + (size_t)8*1024*1024),
                        (float*)(ws + (size_t)12*1024*1024),
                        (float*)(ws + (size_t)16*1024*1024),
                        errF, out, tid, stride, th);
        return;
    }

    // ---------------- power iterations: A (partial SpMV) + B (merge/commit) ----------------
    for (int iter = 0; iter < MAX_ITER; ++iter) {
        if (blk < NSUBB) {
            const int b = blk >> 3, sub = blk & 7;
            for (int j = th; j < 16384; j += T) SH[j] = 0;
            __syncthreads();
            const unsigned bs = baseR[b], tot = totR[b], pt = (tot + 7u) & ~7u;
            const unsigned nq = pt >> 3;
            const unsigned qlo = (nq * (unsigned)sub) >> 3;
            const unsigned qhi = (nq * (unsigned)(sub + 1)) >> 3;
            const vu4* r8 = (const vu4*)wrg + (bs >> 3);
            const vi4* c8 = (const vi4*)wcg + (bs >> 2);
            for (unsigned q = qlo + th; q < qhi; q += T) {
                vu4 rl = ntload(r8 + q);
                vi4 ca = ntload(c8 + 2*q), cb = ntload(c8 + 2*q + 1);
                atomicAdd(&SH[rl.x & 0xFFFFu], __float2int_rn(w[(unsigned)ca.x] * SCALE));
                atomicAdd(&SH[rl.x >> 16],     __float2int_rn(w[(unsigned)ca.y] * SCALE));
                atomicAdd(&SH[rl.y & 0xFFFFu], __float2int_rn(w[(unsigned)ca.z] * SCALE));
                atomicAdd(&SH[rl.y >> 16],     __float2int_rn(w[(unsigned)ca.w] * SCALE));
                atomicAdd(&SH[rl.z & 0xFFFFu], __float2int_rn(w[(unsigned)cb.x] * SCALE));
                atomicAdd(&SH[rl.z >> 16],     __float2int_rn(w[(unsigned)cb.y] * SCALE));
                atomicAdd(&SH[rl.w & 0xFFFFu], __float2int_rn(w[(unsigned)cb.z] * SCALE));
                atomicAdd(&SH[rl.w >> 16],     __float2int_rn(w[(unsigned)cb.w] * SCALE));
            }
            __syncthreads();
            vi4* pa = (vi4*)(pacc + (size_t)blk * 16384);
            const vi4* s4 = (const vi4*)SH;
            for (int j = th; j < 4096; j += T)
                __builtin_nontemporal_store(s4[j], pa + j);
        }
        grid.sync();

        float pe = 0.0f;
        if (blk < NSLC) {
            const int b = blk >> 3, off = (blk & 7) * 2048;
            for (int g = th; g < 512; g += T) {
                int node = b * BKN + off + 4 * g;
                if (node < NN) {
                    vi4 acc = {0, 0, 0, 0};
                    #pragma unroll
                    for (int p = 0; p < 8; ++p) {
                        const vi4* pp = (const vi4*)(pacc + (size_t)(b*8+p)*16384 + off);
                        vi4 x = ntload(pp + g);
                        acc.x += x.x; acc.y += x.y; acc.z += x.z; acc.w += x.w;
                    }
                    float x0 = TELEPORT + (float)acc.x * INVSCALE;
                    float x1 = TELEPORT + (float)acc.y * INVSCALE;
                    float x2 = TELEPORT + (float)acc.z * INVSCALE;
                    float x3 = TELEPORT + (float)acc.w * INVSCALE;
                    float4 prev;
                    if (iter == 0) prev = make_float4(INV_N, INV_N, INV_N, INV_N);
                    else           prev = *(const float4*)&out[node];
                    pe += fabsf(x0 - prev.x) + fabsf(x1 - prev.y)
                        + fabsf(x2 - prev.z) + fabsf(x3 - prev.w);
                    float4 nv = {x0, x1, x2, x3};
                    *(float4*)&out[node] = nv;                 // v lives in out
                    float4 rd = *(const float4*)&rdeg[node];
                    float4 nw = {x0*rd.x, x1*rd.y, x2*rd.z, x3*rd.w};
                    *(float4*)&w[node] = nw;                   // fused next-iter phase A
                }
            }
            #pragma unroll
            for (int off2 = 32; off2 > 0; off2 >>= 1) pe += __shfl_down(pe, off2, 64);
            if ((th & 63) == 0) sred[th >> 6] = pe;
            __syncthreads();
            if (th == 0)
                unsafeAtomicAdd(&errF[iter], sred[0] + sred[1] + sred[2] + sred[3]);
        }
        grid.sync();
        const float e = ((volatile float*)errF)[iter];
        if (e < THRESH) break;
    }
    // out holds the last committed iterate (reference semantics: the iteration
    // whose err first drops below thresh IS committed; later ones are frozen).
}

// ---- emergency fallback kernel (ws too small / occupancy short) ----
__global__ __launch_bounds__(256, 4)
void pagerank_atomic(const int* __restrict__ e32, const long long* __restrict__ e64,
                     int* __restrict__ ai, int* __restrict__ deg,
                     float* __restrict__ rdeg, float* __restrict__ vA,
                     float* __restrict__ vB, float* __restrict__ w,
                     float* __restrict__ err, int* __restrict__ flags,
                     float* __restrict__ out)
{
    cg::grid_group grid = cg::this_grid();
    const int tid = blockIdx.x * blockDim.x + threadIdx.x;
    const int stride = gridDim.x * blockDim.x;
    if (tid < MAX_ITER) err[tid] = 0.0f;
    if (tid == 0) {
        int nz = 0;
        for (int k = 1; k < 512; k += 2) nz |= e32[k];
        flags[0] = (nz == 0) ? 1 : 0;
    }
    grid.sync();
    atomic_fallback(grid, flags[0], e32, e64, ai, deg, rdeg, vA, vB, w, err, out,
                    tid, stride, threadIdx.x);
}

extern "C" void kernel_launch(void* const* d_in, const int* in_sizes, int n_in,
                              void* d_out, int out_size, void* d_ws, size_t ws_size,
                              hipStream_t stream)
{
    (void)n_in; (void)out_size;
    const int*       e32 = (const int*)d_in[1];
    const long long* e64 = (const long long*)d_in[1];
    float* out = (float*)d_out;
    char*  ws  = (char*)d_ws;

    int occ = 0;
    hipOccupancyMaxActiveBlocksPerMultiprocessor(&occ, (const void*)pagerank_r8, T, 0);

    if (ws_size >= NEED && occ >= 2) {
        void* args[] = { (void*)&e32, (void*)&e64, (void*)&ws, (void*)&out };
        hipLaunchCooperativeKernel((const void*)pagerank_r8,
                                   dim3(G), dim3(T), args, 0, stream);
        return;
    }

    // emergency: device-atomic version, small footprint
    const size_t MB = 1024 * 1024;
    int*   ai    = (int*)(ws);
    int*   deg   = (int*)(ws + 4 * MB);
    float* rdeg  = (float*)(ws + 8 * MB);
    float* vA    = (float*)(ws + 12 * MB);
    float* vB    = (float*)(ws + 16 * MB);
    float* w     = (float*)(ws + 20 * MB);
    float* err   = (float*)(ws + 24 * MB);
    int*   flg   = (int*)(ws + 24 * MB + 4096);
    int occ2 = 0;
    hipOccupancyMaxActiveBlocksPerMultiprocessor(&occ2, (const void*)pagerank_atomic, 256, 0);
    if (occ2 < 1) occ2 = 1;
    int grid = occ2 * 256; if (grid > 2048) grid = 2048;
    void* args[] = { (void*)&e32, (void*)&e64, (void*)&ai, (void*)&deg, (void*)&rdeg,
                     (void*)&vA, (void*)&vB, (void*)&w, (void*)&err, (void*)&flg,
                     (void*)&out };
    hipLaunchCooperativeKernel((const void*)pagerank_atomic,
                               dim3(grid), dim3(256), args, 0, stream);
}

// Round 9
// 613.883 us; speedup vs baseline: 3.3735x; 1.8098x over previous
//
#include <hip/hip_runtime.h>
#include <hip/hip_cooperative_groups.h>

namespace cg = cooperative_groups;

// PageRank R9: kernel-pipeline restructure of R8. R8 post-mortem: partition
// phases dominated (~800us) because the monolithic cooperative kernel pinned
// ALL phases at 2 blocks/CU (64KB LDS) -> 8 waves/CU -> MLP-starved ~520GB/s.
// R9 splits phases into plain kernels (free barriers, per-phase occupancy):
// K1 hist @32 waves/CU, K3a col-scatter @6 blk/CU, K3b row-scatter @3 blk/CU,
// with register-pipelined batch loads; only the data-dependent iteration loop
// stays cooperative (K5). All R7/R8-proven machinery (exact-placement rings,
// whole-wave contiguous flushes, LDS fixed-point accumulate) is kept.

static constexpr int   NN       = 1000000;
static constexpr int   NE       = 16000000;
static constexpr float ALPHA    = 0.85f;
static constexpr int   MAX_ITER = 100;
static constexpr float THRESH   = 1.0f;                      // float32(N)*1e-6
static constexpr float INV_N    = 1.0f / 1000000.0f;
static constexpr float TELEPORT = 0.15f * (1.0f / 1000000.0f);
static constexpr float SCALE    = 8796093022208.0f;          // 2^43
static constexpr float INVSCALE = 1.0f / 8796093022208.0f;

static constexpr int T     = 256;
static constexpr int NCH   = 2048;           // partition chunks (=K1/K3 grids)
static constexpr int BSH   = 14;
static constexpr int BKN   = 16384;          // nodes per bucket
static constexpr int NBK   = 64;             // buckets (62 used)
static constexpr int NSUBB = 496;            // 62 x 8 SpMV/deg partials
static constexpr int NSLC  = 489;            // 2048-node merge slices

// ws layout (bytes); colp+hpart overlay wcg (dead before K3b writes wcg)
static constexpr size_t OFF_WCG  = 0;                  // (NE+512) u32
static constexpr size_t OFF_COLP = 0;                  // (NE+512) u16 overlay
static constexpr size_t OFF_HP   = 32001024;           // 496*16384 u16 overlay
static constexpr size_t OFF_WRG  = 64002048;           // (NE+512) u16
static constexpr size_t OFF_PACC = 96003072;           // 496*16384 i32
static constexpr size_t OFF_CNTR = 128508928;          // 64*2048 u32
static constexpr size_t OFF_CNTC = 129033216;          // 64*2048 u32
static constexpr size_t OFF_CTRL = 129557504;          // 4KB
static constexpr size_t OFF_RDEG = 129561600;          // 4,000,000
static constexpr size_t OFF_W    = 133561600;          // 4,000,032 (w[NN]=0)
static constexpr size_t NEED     = 137561632;

typedef int      vi4 __attribute__((ext_vector_type(4)));
typedef unsigned vu4 __attribute__((ext_vector_type(4)));

template<typename TT>
__device__ __forceinline__ TT ntload(const TT* p) { return __builtin_nontemporal_load(p); }

struct P {
    unsigned* wcg; unsigned short* colp; unsigned short* hpart; unsigned short* wrg;
    int* pacc; unsigned* cntR; unsigned* cntC;
    float* rdeg; float* w;
    unsigned* totR; unsigned* totC; unsigned* baseR; unsigned* baseC;
    unsigned* flags; int* ovf; float* errF;
};
__device__ __forceinline__ P mk(char* ws) {
    P p;
    p.wcg  = (unsigned*)(ws + OFF_WCG);
    p.colp = (unsigned short*)(ws + OFF_COLP);
    p.hpart= (unsigned short*)(ws + OFF_HP);
    p.wrg  = (unsigned short*)(ws + OFF_WRG);
    p.pacc = (int*)(ws + OFF_PACC);
    p.cntR = (unsigned*)(ws + OFF_CNTR);
    p.cntC = (unsigned*)(ws + OFF_CNTC);
    unsigned* ctrl = (unsigned*)(ws + OFF_CTRL);
    p.rdeg = (float*)(ws + OFF_RDEG);
    p.w    = (float*)(ws + OFF_W);
    p.totR = ctrl; p.totC = ctrl + 64; p.baseR = ctrl + 128; p.baseC = ctrl + 200;
    p.flags = ctrl + 280; p.ovf = (int*)(ctrl + 281); p.errF = (float*)(ctrl + 288);
    return p;
}

// ---- atomic fallback (is64 input / ring overflow / small ws). No __shared__. ----
__device__ void atomic_fallback(cg::grid_group& grid, int is64,
                                const int* e32, const long long* e64,
                                int* ai, int* deg, float* rdeg,
                                float* vA, float* vB, float* w,
                                float* err, float* out,
                                int tid, int stride, int th)
{
    for (int i = tid; i < NN; i += stride) { ai[i] = 0; deg[i] = 0; vA[i] = INV_N; }
    grid.sync();
    if (is64) { const long long* cols = e64 + NE;
        for (int e = tid; e < NE; e += stride) atomicAdd(&deg[(int)cols[e]], 1); }
    else      { const int* cols = e32 + NE;
        for (int e = tid; e < NE; e += stride) atomicAdd(&deg[cols[e]], 1); }
    grid.sync();
    for (int i = tid; i < NN; i += stride) rdeg[i] = ALPHA / (float)deg[i];
    grid.sync();
    float* v = vA; float* nv = vB;
    for (int iter = 0; iter < MAX_ITER; ++iter) {
        for (int i = tid; i < NN; i += stride) { w[i] = v[i] * rdeg[i]; ai[i] = 0; }
        grid.sync();
        if (is64) { const long long* rows = e64; const long long* cols = e64 + NE;
            for (int e = tid; e < NE; e += stride)
                atomicAdd(&ai[(int)rows[e]], __float2int_rn(w[(int)cols[e]] * SCALE)); }
        else { const int* rows = e32; const int* cols = e32 + NE;
            for (int e = tid; e < NE; e += stride)
                atomicAdd(&ai[rows[e]], __float2int_rn(w[cols[e]] * SCALE)); }
        grid.sync();
        float pe = 0.0f;
        for (int i = tid; i < NN; i += stride) {
            float x = TELEPORT + (float)ai[i] * INVSCALE;
            pe += fabsf(x - v[i]); nv[i] = x;
        }
        #pragma unroll
        for (int off = 32; off > 0; off >>= 1) pe += __shfl_down(pe, off, 64);
        if ((th & 63) == 0) unsafeAtomicAdd(&err[iter], pe);
        grid.sync();
        float e = ((volatile float*)err)[iter];
        float* t = v; v = nv; nv = t;
        if (e < THRESH) break;
    }
    for (int i = tid; i < NN; i += stride) out[i] = v[i];
}

// ---------------- K0: flags / control init ----------------
__global__ __launch_bounds__(256) void k0_init(const int* __restrict__ e32, char* ws)
{
    P p = mk(ws);
    __shared__ int snz;
    const int th = threadIdx.x;
    if (th == 0) snz = 0;
    __syncthreads();
    if (e32[2 * th + 1] != 0) atomicOr(&snz, 1);   // int64 => high words all 0
    __syncthreads();
    if (th == 0) { p.flags[0] = (snz == 0) ? 1u : 0u; *p.ovf = 0; p.w[NN] = 0.0f; }
    if (th < MAX_ITER) p.errF[th] = 0.0f;
}

// ---------------- K1: per-chunk bucket histograms ----------------
__global__ __launch_bounds__(256, 8) void k1_hist(const int* __restrict__ e32, char* ws)
{
    P p = mk(ws);
    if (p.flags[0]) return;
    __shared__ int h[128];
    const int th = threadIdx.x, blk = blockIdx.x;
    const int e0 = (int)(((long long)NE * blk) >> 11);
    const int e1 = (int)(((long long)NE * (blk + 1)) >> 11);
    if (th < 128) h[th] = 0;
    __syncthreads();
    const vi4* R4 = (const vi4*)e32;
    const vi4* C4 = (const vi4*)(e32 + NE);
    const int qe = (e1 + 3) >> 2;
    for (int q = (e0 >> 2) + th; q < qe; q += T) {
        vi4 R = R4[q], C = C4[q];                  // plain loads: seed L3 for K3
        int rr[4] = {R.x, R.y, R.z, R.w}, cc[4] = {C.x, C.y, C.z, C.w};
        #pragma unroll
        for (int j = 0; j < 4; ++j) {
            int e = 4 * q + j;
            if (e >= e0 && e < e1) {
                atomicAdd(&h[rr[j] >> BSH], 1);
                atomicAdd(&h[64 + (cc[j] >> BSH)], 1);
            }
        }
    }
    __syncthreads();
    if (th < 64) {
        p.cntR[(size_t)th * NCH + blk] = (unsigned)h[th];
        p.cntC[(size_t)th * NCH + blk] = (unsigned)h[64 + th];
    }
}

// ---------------- K2: per-bucket exclusive scan over 2048 chunks ----------------
__global__ __launch_bounds__(256, 4) void k2_scan(char* ws)
{
    P p = mk(ws);
    if (p.flags[0]) return;
    __shared__ int S[256];
    const int th = threadIdx.x, blk = blockIdx.x;     // 128 blocks
    const int side = blk >> 6, b = blk & 63;
    unsigned* cnt = (side ? p.cntC : p.cntR) + (size_t)b * NCH;
    unsigned v[8]; unsigned s = 0;
    #pragma unroll
    for (int i = 0; i < 8; ++i) { v[i] = cnt[8 * th + i]; s += v[i]; }
    S[th] = (int)s; __syncthreads();
    for (int off = 1; off < 256; off <<= 1) {
        int x = (th >= off) ? S[th - off] : 0;
        __syncthreads(); S[th] += x; __syncthreads();
    }
    unsigned run = (unsigned)S[th] - s;
    #pragma unroll
    for (int i = 0; i < 8; ++i) { unsigned t = v[i]; cnt[8 * th + i] = run; run += t; }
    if (th == 255) (side ? p.totC : p.totR)[b] = run;
}

// ---------------- K2b: padded bases + col pads ----------------
__global__ __launch_bounds__(256) void k2b_bases(char* ws)
{
    P p = mk(ws);
    if (p.flags[0]) return;
    __shared__ int S[128];
    const int th = threadIdx.x;
    unsigned pt = 0;
    if (th < 128) {
        unsigned t = (th < 64) ? p.totR[th] : p.totC[th - 64];
        pt = (t + 7u) & ~7u;
        S[th] = (int)pt;
    }
    __syncthreads();
    for (int off = 1; off < 64; off <<= 1) {
        int x = (th < 128 && (th & 63) >= off) ? S[th - off] : 0;
        __syncthreads(); if (th < 128) S[th] += x; __syncthreads();
    }
    if (th < 64) {
        p.baseR[th] = (unsigned)S[th] - pt;
        if (th == 63) p.baseR[64] = (unsigned)S[63];
    } else if (th < 128) {
        p.baseC[th - 64] = (unsigned)S[th] - pt;
        if (th == 127) p.baseC[64] = (unsigned)S[127];
    }
    __syncthreads();
    if (th < 64) {                                   // col pads (deg corrected in K4b)
        unsigned tot = p.totC[th], bs = p.baseC[th], pp = (tot + 7u) & ~7u;
        for (unsigned i = tot; i < pp; ++i) p.colp[bs + i] = 0;
    }
}

// ---------------- K3a: col scatter (u16), register-pipelined ----------------
__global__ __launch_bounds__(256, 6) void k3a_col(const int* __restrict__ e32, char* ws)
{
    P p = mk(ws);
    if (p.flags[0]) return;
    __shared__ int SH3[4288];
    unsigned short* pcL = (unsigned short*)SH3;              // [64][128]
    int* fills = SH3 + 4096; int* flsh = SH3 + 4160; int* wpos = SH3 + 4224;
    const int th = threadIdx.x, blk = blockIdx.x;
    if (th < 64) { fills[th] = 0; flsh[th] = 0;
                   wpos[th] = (int)(p.baseC[th] + p.cntC[(size_t)th * NCH + blk]); }
    __syncthreads();
    const int e0 = (int)(((long long)NE * blk) >> 11);
    const int e1 = (int)(((long long)NE * (blk + 1)) >> 11);
    const vi4* C4 = (const vi4*)(e32 + NE);
    const int qs = e0 >> 2, qe = (e1 + 3) >> 2;
    vi4 Ccur = {0, 0, 0, 0}; if (qs + th < qe) Ccur = C4[qs + th];
    for (int qb = qs; qb < qe; qb += T) {
        vi4 Cnext = {0, 0, 0, 0};
        { int qn = qb + T + th; if (qn < qe) Cnext = C4[qn]; }   // prefetch next batch
        const int q = qb + th;
        if (q < qe) {
            int cc[4] = {Ccur.x, Ccur.y, Ccur.z, Ccur.w};
            #pragma unroll
            for (int j = 0; j < 4; ++j) {
                int e = 4 * q + j;
                if (e >= e0 && e < e1) {
                    int bb = cc[j] >> BSH;
                    int idx = atomicAdd(&fills[bb], 1);
                    pcL[bb * 128 + (idx & 127)] = (unsigned short)(cc[j] & (BKN - 1));
                }
            }
        }
        __syncthreads();
        const int wv = th >> 6, lane = th & 63;
        for (int k = 0; k < 16; ++k) {
            const int b = wv * 16 + k;
            int ff = fills[b], fl = flsh[b], wp = wpos[b];
            if (ff - fl > 128) *p.ovf = 1;
            while (ff - fl >= 64) {
                p.colp[wp + lane] = pcL[b * 128 + ((fl + lane) & 127)];
                fl += 64; wp += 64;
            }
            if (lane == 0) { flsh[b] = fl; wpos[b] = wp; }
        }
        __syncthreads();
        Ccur = Cnext;
    }
    {   // drain
        const int wv = th >> 6, lane = th & 63;
        for (int k = 0; k < 16; ++k) {
            const int b = wv * 16 + k;
            int ff = fills[b], fl = flsh[b], wp = wpos[b];
            while (ff > fl) {
                int n = min(64, ff - fl);
                if (lane < n) p.colp[wp + lane] = pcL[b * 128 + ((fl + lane) & 127)];
                fl += n; wp += n;
            }
        }
    }
}

// ---------------- K4a: 8-way degree partial histograms ----------------
__global__ __launch_bounds__(256, 2) void k4a_deg(char* ws)
{
    P p = mk(ws);
    if (p.flags[0] || *p.ovf) return;
    __shared__ int SH[16384];
    const int th = threadIdx.x, blk = blockIdx.x;            // 496 blocks
    const int b = blk >> 3, sub = blk & 7;
    for (int j = th; j < 16384; j += T) SH[j] = 0;
    __syncthreads();
    const unsigned bs = p.baseC[b], tot = p.totC[b], pt = (tot + 7u) & ~7u;
    const unsigned nq = pt >> 3;
    const unsigned qlo = (nq * (unsigned)sub) >> 3;
    const unsigned qhi = (nq * (unsigned)(sub + 1)) >> 3;
    const vu4* p8 = (const vu4*)p.colp + (bs >> 3);
    for (unsigned q = qlo + th; q < qhi; q += T) {
        vu4 x = ntload(p8 + q);
        atomicAdd(&SH[x.x & 0xFFFFu], 1); atomicAdd(&SH[x.x >> 16], 1);
        atomicAdd(&SH[x.y & 0xFFFFu], 1); atomicAdd(&SH[x.y >> 16], 1);
        atomicAdd(&SH[x.z & 0xFFFFu], 1); atomicAdd(&SH[x.z >> 16], 1);
        atomicAdd(&SH[x.w & 0xFFFFu], 1); atomicAdd(&SH[x.w >> 16], 1);
    }
    __syncthreads();
    unsigned* hp = (unsigned*)(p.hpart + (size_t)blk * 16384);
    for (int j = th; j < 8192; j += T)
        __builtin_nontemporal_store(
            (unsigned)((SH[2*j] & 0xFFFF) | (SH[2*j+1] << 16)), hp + j);
}

// ---------------- K4b: merge deg partials -> rdeg, w0 ----------------
__global__ __launch_bounds__(256, 8) void k4b_merge(char* ws)
{
    P p = mk(ws);
    if (p.flags[0] || *p.ovf) return;
    const int th = threadIdx.x, blk = blockIdx.x;            // 489 blocks
    const int b = blk >> 3, off = (blk & 7) * 2048;
    const unsigned padC = ((p.totC[b] + 7u) & ~7u) - p.totC[b];
    for (int j = th; j < 1024; j += T) {
        unsigned lo = 0, hi = 0;
        #pragma unroll
        for (int q = 0; q < 8; ++q) {
            const unsigned* hp = (const unsigned*)(p.hpart + (size_t)(b*8+q)*16384 + off);
            unsigned x = ntload(hp + j);
            lo += x & 0xFFFFu; hi += x >> 16;
        }
        if (off == 0 && j == 0) lo -= padC;
        int node = b * BKN + off + 2 * j;
        if (node < NN) {
            float r0 = ALPHA / (float)(int)lo;   // deg==0 -> inf, never gathered
            float r1 = ALPHA / (float)(int)hi;
            float2 rr = {r0, r1};
            *(float2*)&p.rdeg[node] = rr;
            float2 ww = {INV_N * r0, INV_N * r1};
            *(float2*)&p.w[node] = ww;           // fused iter-0 phase A
        }
    }
}

// ---------------- K3b: row scatter (u32 c + u16 r_low), register-pipelined ----------------
__global__ __launch_bounds__(256, 3) void k3b_row(const int* __restrict__ e32, char* ws)
{
    P p = mk(ws);
    if (p.flags[0] || *p.ovf) return;
    __shared__ int SH3[12480];
    int*            wcL = SH3;                               // [64][128] u32
    unsigned short* wrL = (unsigned short*)(SH3 + 8192);     // [64][128] u16
    int* fills = SH3 + 12288; int* flsh = SH3 + 12352; int* wpos = SH3 + 12416;
    const int th = threadIdx.x, blk = blockIdx.x;
    if (blk < 64 && th == 0) {                               // row pads
        unsigned tot = p.totR[blk], bs = p.baseR[blk], pt = (tot + 7u) & ~7u;
        for (unsigned i = tot; i < pt; ++i) { p.wcg[bs + i] = (unsigned)NN; p.wrg[bs + i] = 0; }
    }
    if (th < 64) { fills[th] = 0; flsh[th] = 0;
                   wpos[th] = (int)(p.baseR[th] + p.cntR[(size_t)th * NCH + blk]); }
    __syncthreads();
    const int e0 = (int)(((long long)NE * blk) >> 11);
    const int e1 = (int)(((long long)NE * (blk + 1)) >> 11);
    const vi4* R4 = (const vi4*)e32;
    const vi4* C4 = (const vi4*)(e32 + NE);
    const int qs = e0 >> 2, qe = (e1 + 3) >> 2;
    vi4 Rcur = {0,0,0,0}, Ccur = {0,0,0,0};
    if (qs + th < qe) { Rcur = R4[qs + th]; Ccur = C4[qs + th]; }
    for (int qb = qs; qb < qe; qb += T) {
        vi4 Rnext = {0,0,0,0}, Cnext = {0,0,0,0};
        { int qn = qb + T + th; if (qn < qe) { Rnext = R4[qn]; Cnext = C4[qn]; } }
        const int q = qb + th;
        if (q < qe) {
            int rr[4] = {Rcur.x, Rcur.y, Rcur.z, Rcur.w};
            int cc[4] = {Ccur.x, Ccur.y, Ccur.z, Ccur.w};
            #pragma unroll
            for (int j = 0; j < 4; ++j) {
                int e = 4 * q + j;
                if (e >= e0 && e < e1) {
                    int bb = rr[j] >> BSH;
                    int idx = atomicAdd(&fills[bb], 1);
                    int sl = idx & 127;
                    wcL[bb * 128 + sl] = cc[j];
                    wrL[bb * 128 + sl] = (unsigned short)(rr[j] & (BKN - 1));
                }
            }
        }
        __syncthreads();
        const int wv = th >> 6, lane = th & 63;
        for (int k = 0; k < 16; ++k) {
            const int b = wv * 16 + k;
            int ff = fills[b], fl = flsh[b], wp = wpos[b];
            if (ff - fl > 128) *p.ovf = 1;
            while (ff - fl >= 64) {
                p.wcg[wp + lane] = (unsigned)wcL[b * 128 + ((fl + lane) & 127)];
                p.wrg[wp + lane] = wrL[b * 128 + ((fl + lane) & 127)];
                fl += 64; wp += 64;
            }
            if (lane == 0) { flsh[b] = fl; wpos[b] = wp; }
        }
        __syncthreads();
        Rcur = Rnext; Ccur = Cnext;
    }
    {   // drain
        const int wv = th >> 6, lane = th & 63;
        for (int k = 0; k < 16; ++k) {
            const int b = wv * 16 + k;
            int ff = fills[b], fl = flsh[b], wp = wpos[b];
            while (ff > fl) {
                int n = min(64, ff - fl);
                if (lane < n) {
                    p.wcg[wp + lane] = (unsigned)wcL[b * 128 + ((fl + lane) & 127)];
                    p.wrg[wp + lane] = wrL[b * 128 + ((fl + lane) & 127)];
                }
                fl += n; wp += n;
            }
        }
    }
}

// ---------------- K5: cooperative iteration loop (early exit) ----------------
__global__ __launch_bounds__(256, 2)
void k5_iter(const int* __restrict__ e32, const long long* __restrict__ e64,
             char* __restrict__ ws, float* __restrict__ out)
{
    cg::grid_group grid = cg::this_grid();
    P p = mk(ws);
    const int th = threadIdx.x, blk = blockIdx.x;
    const int tid = blk * T + th;
    const int stride = gridDim.x * T;
    __shared__ int SH[16384];
    __shared__ float sred[4];

    if (p.flags[0] || *p.ovf) {
        atomic_fallback(grid, (int)p.flags[0], e32, e64,
                        (int*)ws, (int*)(ws + (size_t)4*1024*1024), p.rdeg,
                        (float*)(ws + (size_t)8*1024*1024),
                        (float*)(ws + (size_t)12*1024*1024),
                        (float*)(ws + (size_t)16*1024*1024),
                        p.errF, out, tid, stride, th);
        return;
    }

    for (int iter = 0; iter < MAX_ITER; ++iter) {
        if (blk < NSUBB) {
            const int b = blk >> 3, sub = blk & 7;
            for (int j = th; j < 16384; j += T) SH[j] = 0;
            __syncthreads();
            const unsigned bs = p.baseR[b], tot = p.totR[b], pt = (tot + 7u) & ~7u;
            const unsigned nq = pt >> 3;
            const unsigned qlo = (nq * (unsigned)sub) >> 3;
            const unsigned qhi = (nq * (unsigned)(sub + 1)) >> 3;
            const vu4* r8 = (const vu4*)p.wrg + (bs >> 3);
            const vi4* c8 = (const vi4*)p.wcg + (bs >> 2);
            for (unsigned q = qlo + th; q < qhi; q += T) {
                vu4 rl = ntload(r8 + q);
                vi4 ca = ntload(c8 + 2*q), cb = ntload(c8 + 2*q + 1);
                atomicAdd(&SH[rl.x & 0xFFFFu], __float2int_rn(p.w[(unsigned)ca.x] * SCALE));
                atomicAdd(&SH[rl.x >> 16],     __float2int_rn(p.w[(unsigned)ca.y] * SCALE));
                atomicAdd(&SH[rl.y & 0xFFFFu], __float2int_rn(p.w[(unsigned)ca.z] * SCALE));
                atomicAdd(&SH[rl.y >> 16],     __float2int_rn(p.w[(unsigned)ca.w] * SCALE));
                atomicAdd(&SH[rl.z & 0xFFFFu], __float2int_rn(p.w[(unsigned)cb.x] * SCALE));
                atomicAdd(&SH[rl.z >> 16],     __float2int_rn(p.w[(unsigned)cb.y] * SCALE));
                atomicAdd(&SH[rl.w & 0xFFFFu], __float2int_rn(p.w[(unsigned)cb.z] * SCALE));
                atomicAdd(&SH[rl.w >> 16],     __float2int_rn(p.w[(unsigned)cb.w] * SCALE));
            }
            __syncthreads();
            vi4* pa = (vi4*)(p.pacc + (size_t)blk * 16384);
            const vi4* s4 = (const vi4*)SH;
            for (int j = th; j < 4096; j += T)
                __builtin_nontemporal_store(s4[j], pa + j);
        }
        grid.sync();

        float pe = 0.0f;
        if (blk < NSLC) {
            const int b = blk >> 3, off = (blk & 7) * 2048;
            for (int g = th; g < 512; g += T) {
                int node = b * BKN + off + 4 * g;
                if (node < NN) {
                    vi4 acc = {0, 0, 0, 0};
                    #pragma unroll
                    for (int q = 0; q < 8; ++q) {
                        const vi4* pp = (const vi4*)(p.pacc + (size_t)(b*8+q)*16384 + off);
                        vi4 x = ntload(pp + g);
                        acc.x += x.x; acc.y += x.y; acc.z += x.z; acc.w += x.w;
                    }
                    float x0 = TELEPORT + (float)acc.x * INVSCALE;
                    float x1 = TELEPORT + (float)acc.y * INVSCALE;
                    float x2 = TELEPORT + (float)acc.z * INVSCALE;
                    float x3 = TELEPORT + (float)acc.w * INVSCALE;
                    float4 prev;
                    if (iter == 0) prev = make_float4(INV_N, INV_N, INV_N, INV_N);
                    else           prev = *(const float4*)&out[node];
                    pe += fabsf(x0 - prev.x) + fabsf(x1 - prev.y)
                        + fabsf(x2 - prev.z) + fabsf(x3 - prev.w);
                    float4 nv = {x0, x1, x2, x3};
                    *(float4*)&out[node] = nv;                 // v lives in out
                    float4 rd = *(const float4*)&p.rdeg[node];
                    float4 nw = {x0*rd.x, x1*rd.y, x2*rd.z, x3*rd.w};
                    *(float4*)&p.w[node] = nw;                 // fused next phase A
                }
            }
            #pragma unroll
            for (int o2 = 32; o2 > 0; o2 >>= 1) pe += __shfl_down(pe, o2, 64);
            if ((th & 63) == 0) sred[th >> 6] = pe;
            __syncthreads();
            if (th == 0)
                unsafeAtomicAdd(&p.errF[iter], sred[0] + sred[1] + sred[2] + sred[3]);
        }
        grid.sync();
        const float e = ((volatile float*)p.errF)[iter];
        if (e < THRESH) break;
    }
}

// ---- emergency fallback kernel (ws too small / occupancy short) ----
__global__ __launch_bounds__(256, 4)
void pagerank_atomic(const int* __restrict__ e32, const long long* __restrict__ e64,
                     int* __restrict__ ai, int* __restrict__ deg,
                     float* __restrict__ rdeg, float* __restrict__ vA,
                     float* __restrict__ vB, float* __restrict__ w,
                     float* __restrict__ err, int* __restrict__ flags,
                     float* __restrict__ out)
{
    cg::grid_group grid = cg::this_grid();
    const int tid = blockIdx.x * blockDim.x + threadIdx.x;
    const int stride = gridDim.x * blockDim.x;
    if (tid < MAX_ITER) err[tid] = 0.0f;
    if (tid == 0) {
        int nz = 0;
        for (int k = 1; k < 512; k += 2) nz |= e32[k];
        flags[0] = (nz == 0) ? 1 : 0;
    }
    grid.sync();
    atomic_fallback(grid, flags[0], e32, e64, ai, deg, rdeg, vA, vB, w, err, out,
                    tid, stride, threadIdx.x);
}

extern "C" void kernel_launch(void* const* d_in, const int* in_sizes, int n_in,
                              void* d_out, int out_size, void* d_ws, size_t ws_size,
                              hipStream_t stream)
{
    (void)n_in; (void)out_size; (void)in_sizes;
    const int*       e32 = (const int*)d_in[1];
    const long long* e64 = (const long long*)d_in[1];
    float* out = (float*)d_out;
    char*  ws  = (char*)d_ws;

    int occ = 0;
    hipOccupancyMaxActiveBlocksPerMultiprocessor(&occ, (const void*)k5_iter, T, 0);

    if (ws_size >= NEED && occ >= 2) {
        k0_init<<<1,    T, 0, stream>>>(e32, ws);
        k1_hist<<<NCH,  T, 0, stream>>>(e32, ws);
        k2_scan<<<128,  T, 0, stream>>>(ws);
        k2b_bases<<<1,  T, 0, stream>>>(ws);
        k3a_col<<<NCH,  T, 0, stream>>>(e32, ws);
        k4a_deg<<<NSUBB,T, 0, stream>>>(ws);
        k4b_merge<<<NSLC,T,0, stream>>>(ws);
        k3b_row<<<NCH,  T, 0, stream>>>(e32, ws);
        void* args[] = { (void*)&e32, (void*)&e64, (void*)&ws, (void*)&out };
        hipLaunchCooperativeKernel((const void*)k5_iter,
                                   dim3(512), dim3(T), args, 0, stream);
        return;
    }

    // emergency: device-atomic version, small footprint
    const size_t MB = 1024 * 1024;
    int*   ai    = (int*)(ws);
    int*   deg   = (int*)(ws + 4 * MB);
    float* rdeg  = (float*)(ws + 8 * MB);
    float* vA    = (float*)(ws + 12 * MB);
    float* vB    = (float*)(ws + 16 * MB);
    float* w     = (float*)(ws + 20 * MB);
    float* err   = (float*)(ws + 24 * MB);
    int*   flg   = (int*)(ws + 24 * MB + 4096);
    int occ2 = 0;
    hipOccupancyMaxActiveBlocksPerMultiprocessor(&occ2, (const void*)pagerank_atomic, 256, 0);
    if (occ2 < 1) occ2 = 1;
    int grid = occ2 * 256; if (grid > 2048) grid = 2048;
    void* args[] = { (void*)&e32, (void*)&e64, (void*)&ai, (void*)&deg, (void*)&rdeg,
                     (void*)&vA, (void*)&vB, (void*)&w, (void*)&err, (void*)&flg,
                     (void*)&out };
    hipLaunchCooperativeKernel((const void*)pagerank_atomic,
                               dim3(grid), dim3(256), args, 0, stream);
}